// Round 11
// baseline (253.727 us; speedup 1.0000x reference)
//
#include <hip/hip_runtime.h>
#include <stdint.h>

// Problem constants (B=4, C=256, H=W=64, PATCH=3, STRIDE=1)
#define NP   3844   // 62*62 patches == per-batch feat pixels
#define ND   62
#define NC   256
#define HW   64
#define SP   4096   // 64*64 pixels per image
#define SPSP ((size_t)SP * SP)      // H elements per batch
#define NCSP ((size_t)NC * SP)      // panel elements per batch
#define EPS_G 0.15f        // margin: MFMA fp32 accum + stencil adds + subnormals
#define HULP_H 0.0009765625f // 2^-10: FULL ulp factor for fp16 H entries (RTZ hedge)
#define SPLIT_REL 0.0009765625f  // 2^-10: fp16 quantization of both GEMM operands

// Epilogue staging geometry: 65 rows x 132-float stride (34,320 B).
// R6: VGPR 84-92 caps occupancy at 16 waves/CU; LDS<40KB buys nothing.
// R7: barriered LDS-dbuf pipeline <= flat barrier-free loop. Keep R5 flat.
// R8/R9/R10: downstream kernels are L3-resident; traffic math overestimates
// them. R11: stencil was 1-wave-per-query latency-bound -> 2-wave split.
#define EP_ROWS 65
#define EP_LD   132

typedef __attribute__((ext_vector_type(8))) short short8;
typedef __attribute__((ext_vector_type(8))) unsigned short ushort8;
typedef __attribute__((ext_vector_type(8))) _Float16 half8;
typedef __attribute__((ext_vector_type(2))) _Float16 half2v;
typedef __attribute__((ext_vector_type(4))) float float4v;
typedef __attribute__((ext_vector_type(2))) float float2v;
typedef unsigned long long u64;

__device__ __forceinline__ unsigned int orderf(float v) {
    unsigned int u = __float_as_uint(v);
    return (u & 0x80000000u) ? ~u : (u | 0x80000000u);
}
__device__ __forceinline__ float unorderf(unsigned int k) {
    return __uint_as_float((k & 0x80000000u) ? (k ^ 0x80000000u) : ~k);
}

// Bijective XCD-aware block-id swizzle (m204 variant): contiguous chunk per
// XCD so per-XCD L2 caches one batch's panels. Bijective for any nwg.
__device__ __forceinline__ int xcd_swz(int orig, int nwg) {
    const int q = nwg >> 3, r = nwg & 7;
    const int xcd = orig & 7, i = orig >> 3;
    const int base = (xcd < r) ? xcd * (q + 1) : r * (q + 1) + (xcd - r) * q;
    return base + i;
}

// ---------------------------------------------------------------------------
// Kernel 0 (tier-B only): batched [256][4096] -> [4096][256] fp32 transpose
// ---------------------------------------------------------------------------
__global__ __launch_bounds__(256) void transpose_b(
    const float* __restrict__ src0, float* __restrict__ dst0)
{
    const float* src = src0 + (size_t)blockIdx.z * NCSP;
    float* dst = dst0 + (size_t)blockIdx.z * NCSP;
    __shared__ float t[32][33];
    const int s0 = blockIdx.x * 32;
    const int c0 = blockIdx.y * 32;
    const int col = threadIdx.x & 31, r8 = threadIdx.x >> 5;
    #pragma unroll
    for (int i = 0; i < 4; ++i) {
        int r = r8 + i * 8;
        t[r][col] = src[(size_t)(c0 + r) * SP + s0 + col];
    }
    __syncthreads();
    #pragma unroll
    for (int i = 0; i < 4; ++i) {
        int r = r8 + i * 8;
        dst[(size_t)(s0 + r) * 256 + c0 + col] = t[col][r];
    }
}

// ---------------------------------------------------------------------------
// Kernel 0b (tier-B only): column sum-of-squares, c split 4-way.
// ---------------------------------------------------------------------------
__global__ __launch_bounds__(256) void col_sq(
    const float* __restrict__ content, const float* __restrict__ style,
    float* __restrict__ na_c, float* __restrict__ nb_s)
{
    const int blk = blockIdx.x, tid = threadIdx.x, qn = blockIdx.y;
    const float* src;
    float* dst;
    int s;
    if (blk < 64) {
        int b = blk >> 4, ch = blk & 15;
        src = content + (size_t)b * NCSP;
        dst = na_c + b * SP;
        s = ch * 256 + tid;
    } else {
        src = style;
        dst = nb_s;
        s = (blk - 64) * 256 + tid;
    }
    float sum = 0.f;
    const int c0 = qn * 64;
    #pragma unroll 4
    for (int c = c0; c < c0 + 64; ++c) {
        float v = src[(size_t)c * SP + s];
        sum = fmaf(v, v, sum);
    }
    atomicAdd(&dst[s], sum);
}

// ---------------------------------------------------------------------------
// Kernel 0c (tier A, validated R10): FUSED prep — one read of the input:
//  (1) fp32 transpose [s][c], (2) fp16 RNE k-panels, (3) column sum-sq.
// grid (16,8,5): z 0..3 content, 4 style.
// ---------------------------------------------------------------------------
__global__ __launch_bounds__(256) void prep_fused(
    const float* __restrict__ content, const float* __restrict__ style,
    float* __restrict__ content_t, float* __restrict__ style_t,
    unsigned short* __restrict__ PC, unsigned short* __restrict__ PS,
    float* __restrict__ na_c, float* __restrict__ nb_s)
{
    __shared__ float t[32][257];
    const int z = blockIdx.z;
    const float* src;
    float* dt;
    unsigned short* pp;
    float* sqp;
    if (z < 4) {
        src = content + (size_t)z * NCSP;
        dt  = content_t + (size_t)z * NCSP;
        pp  = PC + (size_t)z * NCSP;
        sqp = na_c + z * SP;
    } else {
        src = style;
        dt  = style_t;
        pp  = PS;
        sqp = nb_s;
    }
    const int s0 = blockIdx.x * 256;
    const int c0 = blockIdx.y * 32;
    const int tid = threadIdx.x;

    // load 32 channel-rows x 256 columns (1KB coalesced per row)
    #pragma unroll
    for (int c = 0; c < 32; ++c)
        t[c][tid] = src[(size_t)(c0 + c) * SP + s0 + tid];
    __syncthreads();

    // (1) transpose: thread s=tid writes 32 consecutive c (8x float4)
    #pragma unroll
    for (int i = 0; i < 8; ++i) {
        float4v v;
        v[0] = t[4 * i + 0][tid];
        v[1] = t[4 * i + 1][tid];
        v[2] = t[4 * i + 2][tid];
        v[3] = t[4 * i + 3][tid];
        *(float4v*)(dt + (size_t)(s0 + tid) * 256 + c0 + 4 * i) = v;
    }

    // (2) fp16 panels: 4 kp-groups of 8 channels, 16B store each
    #pragma unroll
    for (int j = 0; j < 4; ++j) {
        ushort8 hv;
        #pragma unroll
        for (int kk = 0; kk < 8; ++kk) {
            _Float16 hf = (_Float16)t[j * 8 + kk][tid];   // RNE
            unsigned short hb;
            __builtin_memcpy(&hb, &hf, 2);
            hv[kk] = hb;
        }
        *(ushort8*)(pp + ((size_t)(c0 / 8 + j) * 4096 + s0 + tid) * 8) = hv;
    }

    // (3) column sum-of-squares over this block's 32 channels
    float sum = 0.f;
    #pragma unroll
    for (int c = 0; c < 32; ++c) {
        float x = t[c][tid];
        sum = fmaf(x, x, sum);
    }
    atomicAdd(&sqp[s0 + tid], sum);
}

// ---------------------------------------------------------------------------
// Shared GEMM epilogue (v2, validated R4/R5): TWO-PASS row-half staging
// through a padded float[65][132] LDS buffer. Pass p stages acc rows
// [63p, 63p+64], computes H rows 63p..63p+62:
//   H(s,t) = G(s,t)+G(s+1,t+1)+G(s+2,t+2), fp16 RNE.
// ---------------------------------------------------------------------------
__device__ __forceinline__ void epilogue_H(
    float* __restrict__ Lt, const float4v acc[4][4],
    int tid, int wm, int wn, int fq, int fr,
    unsigned short* __restrict__ Hb, int s0, int t0)
{
    #pragma unroll
    for (int p = 0; p < 2; ++p) {
        const int rb = p * 63;
        __syncthreads();   // orders prior reads / previous pass
        #pragma unroll
        for (int fm = 0; fm < 4; ++fm) {
            #pragma unroll
            for (int r = 0; r < 4; ++r) {
                const int row = wm + fm * 16 + fq * 4 + r;
                const int lr = row - rb;
                if (lr >= 0 && lr < EP_ROWS) {
                    #pragma unroll
                    for (int fn = 0; fn < 4; ++fn)
                        Lt[lr * EP_LD + wn + fn * 16 + fr] = acc[fm][fn][r];
                }
            }
        }
        __syncthreads();

        for (int task = tid; task < 63 * 16; task += 256) {
            const int rl = task >> 4;          // 0..62 local row
            const int rr = rb + rl;            // global tile row
            const int o  = (task & 15) * 8;
            const float* L0 = Lt + rl * EP_LD + o;
            const float* L1 = L0 + EP_LD;
            const float* L2 = L0 + 2 * EP_LD;
            float4v r0a = *(const float4v*)(L0);
            float4v r0b = *(const float4v*)(L0 + 4);
            float4v r1a = *(const float4v*)(L1);
            float4v r1b = *(const float4v*)(L1 + 4);
            float2v r1c = *(const float2v*)(L1 + 8);
            float4v r2a = *(const float4v*)(L2);
            float4v r2b = *(const float4v*)(L2 + 4);
            float2v r2c = *(const float2v*)(L2 + 8);
            float s_[8];
            s_[0] = r0a[0] + r1a[1] + r2a[2];
            s_[1] = r0a[1] + r1a[2] + r2a[3];
            s_[2] = r0a[2] + r1a[3] + r2b[0];
            s_[3] = r0a[3] + r1b[0] + r2b[1];
            s_[4] = r0b[0] + r1b[1] + r2b[2];
            s_[5] = r0b[1] + r1b[2] + r2b[3];
            s_[6] = r0b[2] + r1b[3] + r2c[0];
            s_[7] = r0b[3] + r1c[0] + r2c[1];
            unsigned short* hp = Hb + (size_t)(s0 + rr) * SP + t0 + o;
            const int kmax = (o == 120) ? 3 : 4;  // cols >=126: next tile's
            #pragma unroll
            for (int k = 0; k < 4; ++k) {
                if (k < kmax) {
                    half2v hv;
                    hv[0] = (_Float16)s_[2 * k];
                    hv[1] = (_Float16)s_[2 * k + 1];
                    *(half2v*)(hp + 2 * k) = hv;
                }
            }
        }
    }
}

// ---------------------------------------------------------------------------
// Kernel 1 (R5-exact, best measured): fp16 panel GEMM, FLAT barrier-free
// main loop (unroll 4) + XCD swizzle + fused two-pass H epilogue.
// ---------------------------------------------------------------------------
__global__ __launch_bounds__(256) void g_gemm_f16(
    const unsigned short* __restrict__ A0,
    const unsigned short* __restrict__ B,
    unsigned short* __restrict__ H0)
{
    __shared__ __attribute__((aligned(16))) float Lt[EP_ROWS * EP_LD];

    // --- bijective XCD swizzle over the flattened 33*33*4 grid ---
    const int orig = blockIdx.x + 33 * blockIdx.y + 1089 * blockIdx.z;
    const int wg = xcd_swz(orig, 4356);
    const int bz = wg / 1089;
    const int rem = wg - bz * 1089;
    const int by = rem / 33;
    const int bx = rem - by * 33;

    const unsigned short* A = A0 + (size_t)bz * NCSP;
    unsigned short* Hb = H0 + (size_t)bz * SPSP;

    const int tid  = threadIdx.x;
    const int s0   = (bx < 32) ? bx * 126 : 3968;
    const int t0   = (by < 32) ? by * 126 : 3968;
    const int wave = tid >> 6, lane = tid & 63;
    const int wm = (wave >> 1) * 64, wn = (wave & 1) * 64;
    const int fr = lane & 15;
    const int fq = lane >> 4;     // k-quad -> panel offset

    float4v acc[4][4];
    #pragma unroll
    for (int i = 0; i < 4; ++i)
        #pragma unroll
        for (int j = 0; j < 4; ++j) acc[i][j] = (float4v)(0.f);

    size_t ra0[4], rb0[4];
    #pragma unroll
    for (int f = 0; f < 4; ++f) {
        ra0[f] = ((size_t)fq * 4096 + s0 + wm + f * 16 + fr) * 8;
        rb0[f] = ((size_t)fq * 4096 + t0 + wn + f * 16 + fr) * 8;
    }

    #pragma unroll 4
    for (int ks = 0; ks < 8; ++ks) {
        const size_t pan = (size_t)ks * 4 * 4096 * 8;
        half8 a[4], b[4];
        #pragma unroll
        for (int f = 0; f < 4; ++f) {
            a[f] = *(const half8*)(A + pan + ra0[f]);
            b[f] = *(const half8*)(B + pan + rb0[f]);
        }
        #pragma unroll
        for (int fm = 0; fm < 4; ++fm)
            #pragma unroll
            for (int fn = 0; fn < 4; ++fn)
                acc[fm][fn] = __builtin_amdgcn_mfma_f32_16x16x32_f16(
                    a[fm], b[fn], acc[fm][fn], 0, 0, 0);
    }

    epilogue_H(Lt, acc, tid, wm, wn, fq, fr, Hb, s0, t0);
}

// ---------------------------------------------------------------------------
// Kernel 1-fallback: LDS-staged bf16x3 GEMM (fp32 in) + fused H epilogue
// ---------------------------------------------------------------------------
__global__ __launch_bounds__(256, 2) void g_gemm(
    const float* __restrict__ contentb,
    const float* __restrict__ style,
    unsigned short* __restrict__ Hb)
{
    __shared__ __attribute__((aligned(16))) char smem[65536];
    short* Ah = (short*)smem;           // 4*128*8 shorts each
    short* Al = Ah + 4096;
    short* Bh = Al + 4096;
    short* Bl = Bh + 4096;

    const int orig = blockIdx.x + 33 * blockIdx.y;
    const int wg = xcd_swz(orig, 1089);
    const int by = wg / 33;
    const int bx = wg - by * 33;

    const int tid  = threadIdx.x;
    const int s0   = (bx < 32) ? bx * 126 : 3968;
    const int t0   = (by < 32) ? by * 126 : 3968;
    const int wave = tid >> 6, lane = tid & 63;
    const int wm = (wave >> 1) * 64, wn = (wave & 1) * 64;
    const int fr = lane & 15;
    const int fq = lane >> 4;
    const int sm = tid & 127;
    const int sl = tid >> 7;

    float4v acc[4][4];
    #pragma unroll
    for (int i = 0; i < 4; ++i)
        #pragma unroll
        for (int j = 0; j < 4; ++j) acc[i][j] = (float4v)(0.f);

    for (int k0 = 0; k0 < 256; k0 += 32) {
        __syncthreads();
        #pragma unroll
        for (int h = 0; h < 2; ++h) {
            const float* src = h ? style : contentb;
            const int rb = h ? t0 : s0;
            short* dh = h ? Bh : Ah;
            short* dl = h ? Bl : Al;
            float v[16];
            #pragma unroll
            for (int j = 0; j < 16; ++j)
                v[j] = src[(size_t)(k0 + sl * 16 + j) * SP + rb + sm];
            short8 h0, h1, l0, l1;
            #pragma unroll
            for (int j = 0; j < 8; ++j) {
                unsigned ua = __float_as_uint(v[j]);
                unsigned ub = __float_as_uint(v[j + 8]);
                h0[j] = (short)(ua >> 16);
                h1[j] = (short)(ub >> 16);
                float ra  = v[j]     - __uint_as_float(ua & 0xffff0000u);
                float rb2 = v[j + 8] - __uint_as_float(ub & 0xffff0000u);
                l0[j] = (short)(__float_as_uint(ra) >> 16);
                l1[j] = (short)(__float_as_uint(rb2) >> 16);
            }
            *(short8*)(dh + ((sl * 2)     * 128 + sm) * 8) = h0;
            *(short8*)(dh + ((sl * 2 + 1) * 128 + sm) * 8) = h1;
            *(short8*)(dl + ((sl * 2)     * 128 + sm) * 8) = l0;
            *(short8*)(dl + ((sl * 2 + 1) * 128 + sm) * 8) = l1;
        }
        __syncthreads();

        short8 ah[4], al[4], bh[4], bl[4];
        #pragma unroll
        for (int f = 0; f < 4; ++f) {
            const int ra = (fq * 128 + wm + f * 16 + fr) * 8;
            const int rb = (fq * 128 + wn + f * 16 + fr) * 8;
            ah[f] = *(const short8*)(Ah + ra);
            al[f] = *(const short8*)(Al + ra);
            bh[f] = *(const short8*)(Bh + rb);
            bl[f] = *(const short8*)(Bl + rb);
        }
        #pragma unroll
        for (int fm = 0; fm < 4; ++fm)
            #pragma unroll
            for (int fn = 0; fn < 4; ++fn) {
                acc[fm][fn] = __builtin_amdgcn_mfma_f32_16x16x32_bf16(ah[fm], bh[fn], acc[fm][fn], 0, 0, 0);
                acc[fm][fn] = __builtin_amdgcn_mfma_f32_16x16x32_bf16(ah[fm], bl[fn], acc[fm][fn], 0, 0, 0);
                acc[fm][fn] = __builtin_amdgcn_mfma_f32_16x16x32_bf16(al[fm], bh[fn], acc[fm][fn], 0, 0, 0);
            }
    }

    epilogue_H((float*)smem, acc, tid, wm, wn, fq, fr, Hb, s0, t0);
}

// ---------------------------------------------------------------------------
// Kernel 2 (v2, NEW): separable stencil on fp16 H with TWO WAVES PER QUERY.
// Wave pair splits the it-range (0-3 / 4-7); identical loads, fv arithmetic,
// 4-slot tournament, and u64 butterfly; pair's 4 finalist keys merged via
// LDS with the same serial-insert logic. 2x parallelism, half the per-wave
// serial chain. Block = 256 thr = 4 waves = 2 queries.
// ---------------------------------------------------------------------------
__global__ __launch_bounds__(256) void stencil_h2(
    const unsigned short* __restrict__ H0,
    const float* __restrict__ enc_bias,
    u64* __restrict__ cand2, int bbase)
{
    __shared__ u64 km[4][2];
    const int bl = blockIdx.y;
    const unsigned short* H = H0 + (size_t)bl * SPSP;
    const int b = bbase + bl;

    const int tid = threadIdx.x;
    const int q = blockIdx.x * 2 + (tid >> 7);   // 2 queries per block
    const int wave = tid >> 6;
    const int wp = wave & 1;                     // it-half within the pair
    const int lane = tid & 63;
    const int y = q / ND, x = q - y * ND;
    const int jg = (lane & 7) * 8;
    const int ig = lane >> 3;
    const unsigned short* Hq0 = H + (size_t)(y * 64 + x) * SP;
    const unsigned short* Hq1 = Hq0 + (size_t)64 * SP;
    const unsigned short* Hq2 = Hq0 + (size_t)128 * SP;

    float fb1[4], fb2[4];
    int   ib1[4], ib2[4];
    #pragma unroll
    for (int s = 0; s < 4; ++s) {
        fb1[s] = -3.0e38f; fb2[s] = -3.0e38f; ib1[s] = 0; ib2[s] = 0;
    }

    for (int it2 = 0; it2 < 4; ++it2) {
        const int i = (wp * 4 + it2) * 8 + ig;
        if (i <= 61) {
            const int t0o = i * 64 + jg;
            half8 w0 = *(const half8*)(Hq0 + t0o);
            half8 w1 = *(const half8*)(Hq1 + t0o + 64);
            half8 w2 = *(const half8*)(Hq2 + t0o + 128);
            // enc bias: 8B-aligned float2 loads ((i*62+jg) even)
            const float* ep = enc_bias + i * ND + jg;
            float eb[8];
            {
                float2v a0 = *(const float2v*)(ep);
                float2v a1 = *(const float2v*)(ep + 2);
                float2v a2 = *(const float2v*)(ep + 4);
                eb[0] = a0[0]; eb[1] = a0[1];
                eb[2] = a1[0]; eb[3] = a1[1];
                eb[4] = a2[0]; eb[5] = a2[1];
                if (jg < 56) {
                    float2v a3 = *(const float2v*)(ep + 6);
                    eb[6] = a3[0]; eb[7] = a3[1];
                } else { eb[6] = 0.f; eb[7] = 0.f; }   // jj=62,63 masked anyway
            }
            const int pq = i * ND + jg;
            #pragma unroll
            for (int j = 0; j < 8; ++j) {
                int jj = jg + j;
                if (jj <= 61) {            // only jg=56, j>=6 masked
                    float fv = ((float)w0[j] + (float)w1[j])
                             + ((float)w2[j] + eb[j]);
                    int p = pq + j;
                    const int s = j >> 1;
                    bool gt1 = fv > fb1[s];
                    bool gt2 = fv > fb2[s];
                    fb2[s] = gt1 ? fb1[s] : (gt2 ? fv : fb2[s]);
                    ib2[s] = gt1 ? ib1[s] : (gt2 ? p  : ib2[s]);
                    fb1[s] = gt1 ? fv : fb1[s];
                    ib1[s] = gt1 ? p  : ib1[s];
                }
            }
        }
    }

    // --- per-lane merge: build 8 finalist keys, serial top-2 (validated) ---
    u64 k1 = 0, k2 = 0;
    #pragma unroll
    for (int s = 0; s < 4; ++s) {
        u64 ka = ((u64)orderf(fb1[s]) << 32) | (unsigned)(NP - 1 - ib1[s]);
        u64 kb = ((u64)orderf(fb2[s]) << 32) | (unsigned)(NP - 1 - ib2[s]);
        if (ka > k1) { k2 = k1; k1 = ka; } else if (ka > k2) k2 = ka;
        if (kb > k1) { k2 = k1; k1 = kb; } else if (kb > k2) k2 = kb;
    }

    // --- 64-lane butterfly (validated) ---
    #pragma unroll
    for (int d = 1; d < 64; d <<= 1) {
        u64 o1 = __shfl_xor(k1, d, 64);
        u64 o2 = __shfl_xor(k2, d, 64);
        u64 hi = k1 > o1 ? k1 : o1;
        u64 lo = k1 > o1 ? o1 : k1;
        u64 m2 = k2 > o2 ? k2 : o2;
        k1 = hi;
        k2 = lo > m2 ? lo : m2;
    }
    if (lane == 0) { km[wave][0] = k1; km[wave][1] = k2; }
    __syncthreads();

    // --- pair merge: leader of each wave-pair merges 4 keys (same logic) ---
    if ((tid & 127) == 0) {
        const int g = tid >> 7;
        u64 m1 = 0, m2 = 0;
        #pragma unroll
        for (int w = 0; w < 2; ++w)
            #pragma unroll
            for (int t = 0; t < 2; ++t) {
                u64 k = km[g * 2 + w][t];
                if (k > m1) { m2 = m1; m1 = k; } else if (k > m2) m2 = k;
            }
        size_t o = (size_t)(b * NP + q) * 2;
        cand2[o] = m1;
        cand2[o + 1] = m2;
    }
}

// ---------------------------------------------------------------------------
// Kernel 3: norm-bound gap-skip + coalesced exact rescore (fp16-H eul)
// ---------------------------------------------------------------------------
__global__ __launch_bounds__(128) void rescore6(
    const float* __restrict__ content_t, // [4][4096][256]
    const float* __restrict__ style_t,   // [4096][256]
    const float* __restrict__ enc_bias,
    const unsigned short* __restrict__ H0,
    const float* __restrict__ na_c,      // [4][4096] sum-of-squares
    const float* __restrict__ nb_s,      // [4096]    sum-of-squares
    const u64* __restrict__ cand2,
    int* __restrict__ idx, int bbase)
{
    __shared__ float sc[2];
    __shared__ int   pp[2];
    const int bl = blockIdx.x / NP;
    const int q  = blockIdx.x - bl * NP;
    const int b  = bbase + bl;
    const int qa = b * NP + q;
    const unsigned short* Hx = H0 + (size_t)bl * SPSP;
    const int tid = threadIdx.x;
    const int wave = tid >> 6, lane = tid & 63;
    const int y = q / ND, x = q - y * ND;

    const u64 k1 = cand2[(size_t)qa * 2];
    const u64 k2 = cand2[(size_t)qa * 2 + 1];
    const int p1 = NP - 1 - (int)(k1 & 0xffffffffu);
    const int p2 = NP - 1 - (int)(k2 & 0xffffffffu);
    const float f1 = unorderf((unsigned int)(k1 >> 32));
    const float f2 = unorderf((unsigned int)(k2 >> 32));

    if (k2 == 0ull) {
        if (tid == 0) idx[qa] = p1;
        return;
    }

    float eul = 0.f;
    {
        const int side = lane >> 4;            // lanes 0-8 -> p1, 16-24 -> p2
        const int d = lane & 15;
        if (side < 2 && d < 9) {
            int u = d / 3, v = d - u * 3;
            int pc = side ? p2 : p1;
            int pi = pc / ND, pj = pc - pi * ND;
            int sd = (y + u) * 64 + (x + v);
            int td = (pi + u) * 64 + (pj + v);
            float t = SPLIT_REL * sqrtf(na_c[b * SP + sd] * nb_s[td]);
            if (v == 0) {   // one full-ulp(H_fp16) per u (3 roundings total)
                unsigned short hh = Hx[(size_t)sd * SP + td];
                float hf = (float)(*(const _Float16*)&hh);
                t += __uint_as_float(__float_as_uint(hf) & 0x7f800000u) * HULP_H;
            }
            eul = t;
        }
    }
    #pragma unroll
    for (int d = 1; d < 64; d <<= 1) eul += __shfl_xor(eul, d, 64);

    if ((f1 - f2) > eul + EPS_G) {
        if (tid == 0) idx[qa] = p1;
        return;
    }

    const int pc = wave ? p2 : p1;
    const int pi = pc / ND, pj = pc - pi * ND;
    const float* ctb = content_t + (size_t)b * NCSP;
    float s = 0.f;
    #pragma unroll
    for (int u = 0; u < 3; ++u) {
        #pragma unroll
        for (int v = 0; v < 3; ++v) {
            const float* cw = ctb + (size_t)((y + u) * 64 + x + v) * 256 + lane * 4;
            const float* sw = style_t + (size_t)((pi + u) * 64 + pj + v) * 256 + lane * 4;
            float4v c4 = *(const float4v*)cw;
            float4v s4 = *(const float4v*)sw;
            s = fmaf(c4[0], s4[0], s);
            s = fmaf(c4[1], s4[1], s);
            s = fmaf(c4[2], s4[2], s);
            s = fmaf(c4[3], s4[3], s);
        }
    }
    #pragma unroll
    for (int d = 32; d; d >>= 1) s += __shfl_xor(s, d, 64);
    if (lane == 0) { sc[wave] = s + enc_bias[pc]; pp[wave] = pc; }
    __syncthreads();
    if (tid == 0) {
        float s0 = sc[0], s1 = sc[1];
        int q0 = pp[0], q1 = pp[1];
        idx[qa] = (s1 > s0 || (s1 == s0 && q1 < q0)) ? q1 : q0;
    }
}

// ---------------------------------------------------------------------------
// Kernel 4 (v3, validated R9): gather-per-output-pixel with REGISTER
// accumulation; patch-row bases precomputed; bit-identical sums.
// ---------------------------------------------------------------------------
__global__ __launch_bounds__(256) void produce_out3(
    const float* __restrict__ style_t,
    const float* __restrict__ dec_bias,
    const float* __restrict__ intra_bias,
    const int* __restrict__ idx,
    float* __restrict__ out)
{
    __shared__ int prow[3][ND];   // pi*64+pj per (u, xx); add u*64+v at use

    const int bh = blockIdx.x;
    const int b = bh >> 6, h = bh & 63;
    const int ch0 = blockIdx.y * 128;
    const int tid = threadIdx.x;

    if (tid < 3 * ND) {
        int u = tid / ND, xx = tid - u * ND;
        int yy = h - u;
        int p = (yy >= 0 && yy < ND) ? idx[b * NP + yy * ND + xx] : 0;
        int pi = p / ND, pj = p - pi * ND;
        prow[u][xx] = pi * 64 + pj;
    }
    __syncthreads();

    const int w  = tid & 63;
    const int cg = tid >> 6;          // 0..3 -> 32 channels each
    const int cb = ch0 + cg * 32;

    float4v acc[8];
    #pragma unroll
    for (int i = 0; i < 8; ++i) acc[i] = (float4v)(0.f);

    #pragma unroll
    for (int u = 0; u < 3; ++u) {
        const int yy = h - u;
        if (yy >= 0 && yy < ND) {
            #pragma unroll
            for (int v = 0; v < 3; ++v) {
                const int xi = w - v;
                if (xi >= 0 && xi < ND) {
                    const int row = prow[u][xi] + u * 64 + v;
                    const float* sw = style_t + (size_t)row * 256 + cb;
                    #pragma unroll
                    for (int i = 0; i < 8; ++i) {
                        float4v s4 = *(const float4v*)(sw + i * 4);
                        acc[i] += s4;
                    }
                }
            }
        }
    }

    const int cu  = (h < 2 ? h : 2) - (h > 61 ? h - 61 : 0) + 1;
    const int cvw = (w < 2 ? w : 2) - (w > 61 ? w - 61 : 0) + 1;
    const float cnt = (float)(cu * cvw);
    #pragma unroll
    for (int i = 0; i < 8; ++i) {
        #pragma unroll
        for (int k = 0; k < 4; ++k) {
            const int c = cb + i * 4 + k;
            float val = (acc[i][k] + dec_bias[c]) / (cnt + intra_bias[c]);
            out[(((size_t)b * NC + c) * 64 + h) * 64 + w] = val;
        }
    }
}

// ---------------------------------------------------------------------------
extern "C" void kernel_launch(void* const* d_in, const int* in_sizes, int n_in,
                              void* d_out, int out_size, void* d_ws, size_t ws_size,
                              hipStream_t stream) {
    const float* content    = (const float*)d_in[0];
    const float* style      = (const float*)d_in[1];
    const float* enc_bias   = (const float*)d_in[2];
    const float* dec_bias   = (const float*)d_in[3];
    const float* intra_bias = (const float*)d_in[4];
    float* out = (float*)d_out;

    const size_t H_BYTES     = SPSP * 2;                   //  33,554,432
    const size_t CAND2_BYTES = (size_t)4 * NP * 2 * 8;     //     246,016
    const size_t IDX_BYTES   = (size_t)4 * NP * 4;         //      61,504
    const size_t ST_BYTES    = NCSP * 4;                   //   4,194,304
    const size_t CT_BYTES    = (size_t)4 * NCSP * 4;       //  16,777,216
    const size_t P16_BYTES   = NCSP * 2;                   //   2,097,152
    const size_t NA_BYTES    = (size_t)4 * SP * 4;         //      65,536
    const size_t NB_BYTES    = (size_t)SP * 4;             //      16,384

    // Tier A: 4 H's resident + fp16 panels + transposes + norms
    const size_t A_OFF_CAND2 = 4 * H_BYTES;
    const size_t A_OFF_IDX   = A_OFF_CAND2 + CAND2_BYTES;
    const size_t A_OFF_ST    = A_OFF_IDX + IDX_BYTES;
    const size_t A_OFF_CT    = A_OFF_ST + ST_BYTES;
    const size_t A_OFF_PS    = A_OFF_CT + CT_BYTES;
    const size_t A_OFF_PC    = A_OFF_PS + P16_BYTES;
    const size_t A_OFF_NA    = A_OFF_PC + 4 * P16_BYTES;
    const size_t A_OFF_NB    = A_OFF_NA + NA_BYTES;
    const size_t NEED_A      = A_OFF_NB + NB_BYTES;

    // Tier B: single H + bf16x3 fp32-input GEMM per batch
    const size_t B_OFF_CAND2 = H_BYTES;
    const size_t B_OFF_IDX   = B_OFF_CAND2 + CAND2_BYTES;
    const size_t B_OFF_ST    = B_OFF_IDX + IDX_BYTES;
    const size_t B_OFF_CT    = B_OFF_ST + ST_BYTES;
    const size_t B_OFF_NA    = B_OFF_CT + CT_BYTES;
    const size_t B_OFF_NB    = B_OFF_NA + NA_BYTES;
    const size_t NEED_B      = B_OFF_NB + NB_BYTES;
    (void)NEED_B;

    if (ws_size >= NEED_A) {
        unsigned short* H4 = (unsigned short*)d_ws;
        u64* cand2      = (u64*)((char*)d_ws + A_OFF_CAND2);
        int* idx        = (int*)((char*)d_ws + A_OFF_IDX);
        float* style_t  = (float*)((char*)d_ws + A_OFF_ST);
        float* content_t = (float*)((char*)d_ws + A_OFF_CT);
        unsigned short* PS = (unsigned short*)((char*)d_ws + A_OFF_PS);
        unsigned short* PC = (unsigned short*)((char*)d_ws + A_OFF_PC);
        float* na_c     = (float*)((char*)d_ws + A_OFF_NA);
        float* nb_s     = (float*)((char*)d_ws + A_OFF_NB);

        hipMemsetAsync((char*)d_ws + A_OFF_NA, 0, NA_BYTES + NB_BYTES, stream);
        prep_fused<<<dim3(16, 8, 5), 256, 0, stream>>>(
            content, style, content_t, style_t, PC, PS, na_c, nb_s);
        g_gemm_f16<<<dim3(33, 33, 4), 256, 0, stream>>>(PC, PS, H4);
        stencil_h2<<<dim3(NP / 2, 4), 256, 0, stream>>>(H4, enc_bias, cand2, 0);
        rescore6<<<dim3(4 * NP), 128, 0, stream>>>(
            content_t, style_t, enc_bias, H4, na_c, nb_s, cand2, idx, 0);
        produce_out3<<<dim3(4 * 64, 2), 256, 0, stream>>>(
            style_t, dec_bias, intra_bias, idx, out);
    } else {
        unsigned short* Hb = (unsigned short*)d_ws;
        u64* cand2      = (u64*)((char*)d_ws + B_OFF_CAND2);
        int* idx        = (int*)((char*)d_ws + B_OFF_IDX);
        float* style_t  = (float*)((char*)d_ws + B_OFF_ST);
        float* content_t = (float*)((char*)d_ws + B_OFF_CT);
        float* na_c     = (float*)((char*)d_ws + B_OFF_NA);
        float* nb_s     = (float*)((char*)d_ws + B_OFF_NB);

        hipMemsetAsync((char*)d_ws + B_OFF_NA, 0, NA_BYTES + NB_BYTES, stream);
        transpose_b<<<dim3(128, 8, 1), 256, 0, stream>>>(style, style_t);
        transpose_b<<<dim3(128, 8, 4), 256, 0, stream>>>(content, content_t);
        col_sq<<<dim3(80, 4), 256, 0, stream>>>(content, style, na_c, nb_s);
        for (int b = 0; b < 4; ++b) {
            g_gemm<<<dim3(33, 33), 256, 0, stream>>>(
                content + (size_t)b * NCSP, style, Hb);
            stencil_h2<<<dim3(NP / 2, 1), 256, 0, stream>>>(Hb, enc_bias, cand2, b);
            rescore6<<<dim3(NP), 128, 0, stream>>>(
                content_t, style_t, enc_bias, Hb, na_c, nb_s, cand2, idx, b);
        }
        produce_out3<<<dim3(4 * 64, 2), 256, 0, stream>>>(
            style_t, dec_bias, intra_bias, idx, out);
    }
}

// Round 12
// 237.431 us; speedup vs baseline: 1.0686x; 1.0686x over previous
//
#include <hip/hip_runtime.h>
#include <stdint.h>

// Problem constants (B=4, C=256, H=W=64, PATCH=3, STRIDE=1)
#define NP   3844   // 62*62 patches == per-batch feat pixels
#define ND   62
#define NC   256
#define HW   64
#define SP   4096   // 64*64 pixels per image
#define SPSP ((size_t)SP * SP)      // H elements per batch
#define NCSP ((size_t)NC * SP)      // panel elements per batch
#define EPS_G 0.15f        // margin: MFMA fp32 accum + stencil adds + subnormals
#define HULP_H 0.0009765625f // 2^-10: FULL ulp factor for fp16 H entries (RTZ hedge)
#define SPLIT_REL 0.0009765625f  // 2^-10: fp16 quantization of both GEMM operands

// Epilogue staging geometry: 65 rows x 132-float stride (34,320 B).
// R6: VGPR 84-92 caps occupancy at 16 waves/CU; LDS<40KB buys nothing.
// R7: barriered LDS-dbuf pipeline <= flat barrier-free loop. Keep R5 flat.
// R8/R9/R10: downstream kernels are L3-resident; traffic math overestimates.
// R11: 2-wave stencil split REGRESSED (butterfly overhead doubled) — 1 wave
// per query is right. R12: rescore fused into the stencil wave (k1/k2 are
// wave-uniform post-butterfly), deleting a launch + cand2 roundtrip.
#define EP_ROWS 65
#define EP_LD   132

typedef __attribute__((ext_vector_type(8))) short short8;
typedef __attribute__((ext_vector_type(8))) unsigned short ushort8;
typedef __attribute__((ext_vector_type(8))) _Float16 half8;
typedef __attribute__((ext_vector_type(2))) _Float16 half2v;
typedef __attribute__((ext_vector_type(4))) float float4v;
typedef __attribute__((ext_vector_type(2))) float float2v;
typedef unsigned long long u64;

__device__ __forceinline__ unsigned int orderf(float v) {
    unsigned int u = __float_as_uint(v);
    return (u & 0x80000000u) ? ~u : (u | 0x80000000u);
}
__device__ __forceinline__ float unorderf(unsigned int k) {
    return __uint_as_float((k & 0x80000000u) ? (k ^ 0x80000000u) : ~k);
}

// Bijective XCD-aware block-id swizzle (m204 variant): contiguous chunk per
// XCD so per-XCD L2 caches one batch's panels. Bijective for any nwg.
__device__ __forceinline__ int xcd_swz(int orig, int nwg) {
    const int q = nwg >> 3, r = nwg & 7;
    const int xcd = orig & 7, i = orig >> 3;
    const int base = (xcd < r) ? xcd * (q + 1) : r * (q + 1) + (xcd - r) * q;
    return base + i;
}

// ---------------------------------------------------------------------------
// Kernel 0 (tier-B only): batched [256][4096] -> [4096][256] fp32 transpose
// ---------------------------------------------------------------------------
__global__ __launch_bounds__(256) void transpose_b(
    const float* __restrict__ src0, float* __restrict__ dst0)
{
    const float* src = src0 + (size_t)blockIdx.z * NCSP;
    float* dst = dst0 + (size_t)blockIdx.z * NCSP;
    __shared__ float t[32][33];
    const int s0 = blockIdx.x * 32;
    const int c0 = blockIdx.y * 32;
    const int col = threadIdx.x & 31, r8 = threadIdx.x >> 5;
    #pragma unroll
    for (int i = 0; i < 4; ++i) {
        int r = r8 + i * 8;
        t[r][col] = src[(size_t)(c0 + r) * SP + s0 + col];
    }
    __syncthreads();
    #pragma unroll
    for (int i = 0; i < 4; ++i) {
        int r = r8 + i * 8;
        dst[(size_t)(s0 + r) * 256 + c0 + col] = t[col][r];
    }
}

// ---------------------------------------------------------------------------
// Kernel 0b (tier-B only): column sum-of-squares, c split 4-way.
// ---------------------------------------------------------------------------
__global__ __launch_bounds__(256) void col_sq(
    const float* __restrict__ content, const float* __restrict__ style,
    float* __restrict__ na_c, float* __restrict__ nb_s)
{
    const int blk = blockIdx.x, tid = threadIdx.x, qn = blockIdx.y;
    const float* src;
    float* dst;
    int s;
    if (blk < 64) {
        int b = blk >> 4, ch = blk & 15;
        src = content + (size_t)b * NCSP;
        dst = na_c + b * SP;
        s = ch * 256 + tid;
    } else {
        src = style;
        dst = nb_s;
        s = (blk - 64) * 256 + tid;
    }
    float sum = 0.f;
    const int c0 = qn * 64;
    #pragma unroll 4
    for (int c = c0; c < c0 + 64; ++c) {
        float v = src[(size_t)c * SP + s];
        sum = fmaf(v, v, sum);
    }
    atomicAdd(&dst[s], sum);
}

// ---------------------------------------------------------------------------
// Kernel 0c (tier A, validated R10): FUSED prep — one read of the input:
//  (1) fp32 transpose [s][c], (2) fp16 RNE k-panels, (3) column sum-sq.
// grid (16,8,5): z 0..3 content, 4 style.
// ---------------------------------------------------------------------------
__global__ __launch_bounds__(256) void prep_fused(
    const float* __restrict__ content, const float* __restrict__ style,
    float* __restrict__ content_t, float* __restrict__ style_t,
    unsigned short* __restrict__ PC, unsigned short* __restrict__ PS,
    float* __restrict__ na_c, float* __restrict__ nb_s)
{
    __shared__ float t[32][257];
    const int z = blockIdx.z;
    const float* src;
    float* dt;
    unsigned short* pp;
    float* sqp;
    if (z < 4) {
        src = content + (size_t)z * NCSP;
        dt  = content_t + (size_t)z * NCSP;
        pp  = PC + (size_t)z * NCSP;
        sqp = na_c + z * SP;
    } else {
        src = style;
        dt  = style_t;
        pp  = PS;
        sqp = nb_s;
    }
    const int s0 = blockIdx.x * 256;
    const int c0 = blockIdx.y * 32;
    const int tid = threadIdx.x;

    // load 32 channel-rows x 256 columns (1KB coalesced per row)
    #pragma unroll
    for (int c = 0; c < 32; ++c)
        t[c][tid] = src[(size_t)(c0 + c) * SP + s0 + tid];
    __syncthreads();

    // (1) transpose: thread s=tid writes 32 consecutive c (8x float4)
    #pragma unroll
    for (int i = 0; i < 8; ++i) {
        float4v v;
        v[0] = t[4 * i + 0][tid];
        v[1] = t[4 * i + 1][tid];
        v[2] = t[4 * i + 2][tid];
        v[3] = t[4 * i + 3][tid];
        *(float4v*)(dt + (size_t)(s0 + tid) * 256 + c0 + 4 * i) = v;
    }

    // (2) fp16 panels: 4 kp-groups of 8 channels, 16B store each
    #pragma unroll
    for (int j = 0; j < 4; ++j) {
        ushort8 hv;
        #pragma unroll
        for (int kk = 0; kk < 8; ++kk) {
            _Float16 hf = (_Float16)t[j * 8 + kk][tid];   // RNE
            unsigned short hb;
            __builtin_memcpy(&hb, &hf, 2);
            hv[kk] = hb;
        }
        *(ushort8*)(pp + ((size_t)(c0 / 8 + j) * 4096 + s0 + tid) * 8) = hv;
    }

    // (3) column sum-of-squares over this block's 32 channels
    float sum = 0.f;
    #pragma unroll
    for (int c = 0; c < 32; ++c) {
        float x = t[c][tid];
        sum = fmaf(x, x, sum);
    }
    atomicAdd(&sqp[s0 + tid], sum);
}

// ---------------------------------------------------------------------------
// Shared GEMM epilogue (v2, validated R4/R5): TWO-PASS row-half staging
// through a padded float[65][132] LDS buffer. Pass p stages acc rows
// [63p, 63p+64], computes H rows 63p..63p+62:
//   H(s,t) = G(s,t)+G(s+1,t+1)+G(s+2,t+2), fp16 RNE.
// ---------------------------------------------------------------------------
__device__ __forceinline__ void epilogue_H(
    float* __restrict__ Lt, const float4v acc[4][4],
    int tid, int wm, int wn, int fq, int fr,
    unsigned short* __restrict__ Hb, int s0, int t0)
{
    #pragma unroll
    for (int p = 0; p < 2; ++p) {
        const int rb = p * 63;
        __syncthreads();   // orders prior reads / previous pass
        #pragma unroll
        for (int fm = 0; fm < 4; ++fm) {
            #pragma unroll
            for (int r = 0; r < 4; ++r) {
                const int row = wm + fm * 16 + fq * 4 + r;
                const int lr = row - rb;
                if (lr >= 0 && lr < EP_ROWS) {
                    #pragma unroll
                    for (int fn = 0; fn < 4; ++fn)
                        Lt[lr * EP_LD + wn + fn * 16 + fr] = acc[fm][fn][r];
                }
            }
        }
        __syncthreads();

        for (int task = tid; task < 63 * 16; task += 256) {
            const int rl = task >> 4;          // 0..62 local row
            const int rr = rb + rl;            // global tile row
            const int o  = (task & 15) * 8;
            const float* L0 = Lt + rl * EP_LD + o;
            const float* L1 = L0 + EP_LD;
            const float* L2 = L0 + 2 * EP_LD;
            float4v r0a = *(const float4v*)(L0);
            float4v r0b = *(const float4v*)(L0 + 4);
            float4v r1a = *(const float4v*)(L1);
            float4v r1b = *(const float4v*)(L1 + 4);
            float2v r1c = *(const float2v*)(L1 + 8);
            float4v r2a = *(const float4v*)(L2);
            float4v r2b = *(const float4v*)(L2 + 4);
            float2v r2c = *(const float2v*)(L2 + 8);
            float s_[8];
            s_[0] = r0a[0] + r1a[1] + r2a[2];
            s_[1] = r0a[1] + r1a[2] + r2a[3];
            s_[2] = r0a[2] + r1a[3] + r2b[0];
            s_[3] = r0a[3] + r1b[0] + r2b[1];
            s_[4] = r0b[0] + r1b[1] + r2b[2];
            s_[5] = r0b[1] + r1b[2] + r2b[3];
            s_[6] = r0b[2] + r1b[3] + r2c[0];
            s_[7] = r0b[3] + r1c[0] + r2c[1];
            unsigned short* hp = Hb + (size_t)(s0 + rr) * SP + t0 + o;
            const int kmax = (o == 120) ? 3 : 4;  // cols >=126: next tile's
            #pragma unroll
            for (int k = 0; k < 4; ++k) {
                if (k < kmax) {
                    half2v hv;
                    hv[0] = (_Float16)s_[2 * k];
                    hv[1] = (_Float16)s_[2 * k + 1];
                    *(half2v*)(hp + 2 * k) = hv;
                }
            }
        }
    }
}

// ---------------------------------------------------------------------------
// Kernel 1 (R5-exact, best measured): fp16 panel GEMM, FLAT barrier-free
// main loop (unroll 4) + XCD swizzle + fused two-pass H epilogue.
// ---------------------------------------------------------------------------
__global__ __launch_bounds__(256) void g_gemm_f16(
    const unsigned short* __restrict__ A0,
    const unsigned short* __restrict__ B,
    unsigned short* __restrict__ H0)
{
    __shared__ __attribute__((aligned(16))) float Lt[EP_ROWS * EP_LD];

    // --- bijective XCD swizzle over the flattened 33*33*4 grid ---
    const int orig = blockIdx.x + 33 * blockIdx.y + 1089 * blockIdx.z;
    const int wg = xcd_swz(orig, 4356);
    const int bz = wg / 1089;
    const int rem = wg - bz * 1089;
    const int by = rem / 33;
    const int bx = rem - by * 33;

    const unsigned short* A = A0 + (size_t)bz * NCSP;
    unsigned short* Hb = H0 + (size_t)bz * SPSP;

    const int tid  = threadIdx.x;
    const int s0   = (bx < 32) ? bx * 126 : 3968;
    const int t0   = (by < 32) ? by * 126 : 3968;
    const int wave = tid >> 6, lane = tid & 63;
    const int wm = (wave >> 1) * 64, wn = (wave & 1) * 64;
    const int fr = lane & 15;
    const int fq = lane >> 4;     // k-quad -> panel offset

    float4v acc[4][4];
    #pragma unroll
    for (int i = 0; i < 4; ++i)
        #pragma unroll
        for (int j = 0; j < 4; ++j) acc[i][j] = (float4v)(0.f);

    size_t ra0[4], rb0[4];
    #pragma unroll
    for (int f = 0; f < 4; ++f) {
        ra0[f] = ((size_t)fq * 4096 + s0 + wm + f * 16 + fr) * 8;
        rb0[f] = ((size_t)fq * 4096 + t0 + wn + f * 16 + fr) * 8;
    }

    #pragma unroll 4
    for (int ks = 0; ks < 8; ++ks) {
        const size_t pan = (size_t)ks * 4 * 4096 * 8;
        half8 a[4], b[4];
        #pragma unroll
        for (int f = 0; f < 4; ++f) {
            a[f] = *(const half8*)(A + pan + ra0[f]);
            b[f] = *(const half8*)(B + pan + rb0[f]);
        }
        #pragma unroll
        for (int fm = 0; fm < 4; ++fm)
            #pragma unroll
            for (int fn = 0; fn < 4; ++fn)
                acc[fm][fn] = __builtin_amdgcn_mfma_f32_16x16x32_f16(
                    a[fm], b[fn], acc[fm][fn], 0, 0, 0);
    }

    epilogue_H(Lt, acc, tid, wm, wn, fq, fr, Hb, s0, t0);
}

// ---------------------------------------------------------------------------
// Kernel 1-fallback: LDS-staged bf16x3 GEMM (fp32 in) + fused H epilogue
// ---------------------------------------------------------------------------
__global__ __launch_bounds__(256, 2) void g_gemm(
    const float* __restrict__ contentb,
    const float* __restrict__ style,
    unsigned short* __restrict__ Hb)
{
    __shared__ __attribute__((aligned(16))) char smem[65536];
    short* Ah = (short*)smem;           // 4*128*8 shorts each
    short* Al = Ah + 4096;
    short* Bh = Al + 4096;
    short* Bl = Bh + 4096;

    const int orig = blockIdx.x + 33 * blockIdx.y;
    const int wg = xcd_swz(orig, 1089);
    const int by = wg / 33;
    const int bx = wg - by * 33;

    const int tid  = threadIdx.x;
    const int s0   = (bx < 32) ? bx * 126 : 3968;
    const int t0   = (by < 32) ? by * 126 : 3968;
    const int wave = tid >> 6, lane = tid & 63;
    const int wm = (wave >> 1) * 64, wn = (wave & 1) * 64;
    const int fr = lane & 15;
    const int fq = lane >> 4;
    const int sm = tid & 127;
    const int sl = tid >> 7;

    float4v acc[4][4];
    #pragma unroll
    for (int i = 0; i < 4; ++i)
        #pragma unroll
        for (int j = 0; j < 4; ++j) acc[i][j] = (float4v)(0.f);

    for (int k0 = 0; k0 < 256; k0 += 32) {
        __syncthreads();
        #pragma unroll
        for (int h = 0; h < 2; ++h) {
            const float* src = h ? style : contentb;
            const int rb = h ? t0 : s0;
            short* dh = h ? Bh : Ah;
            short* dl = h ? Bl : Al;
            float v[16];
            #pragma unroll
            for (int j = 0; j < 16; ++j)
                v[j] = src[(size_t)(k0 + sl * 16 + j) * SP + rb + sm];
            short8 h0, h1, l0, l1;
            #pragma unroll
            for (int j = 0; j < 8; ++j) {
                unsigned ua = __float_as_uint(v[j]);
                unsigned ub = __float_as_uint(v[j + 8]);
                h0[j] = (short)(ua >> 16);
                h1[j] = (short)(ub >> 16);
                float ra  = v[j]     - __uint_as_float(ua & 0xffff0000u);
                float rb2 = v[j + 8] - __uint_as_float(ub & 0xffff0000u);
                l0[j] = (short)(__float_as_uint(ra) >> 16);
                l1[j] = (short)(__float_as_uint(rb2) >> 16);
            }
            *(short8*)(dh + ((sl * 2)     * 128 + sm) * 8) = h0;
            *(short8*)(dh + ((sl * 2 + 1) * 128 + sm) * 8) = h1;
            *(short8*)(dl + ((sl * 2)     * 128 + sm) * 8) = l0;
            *(short8*)(dl + ((sl * 2 + 1) * 128 + sm) * 8) = l1;
        }
        __syncthreads();

        short8 ah[4], al[4], bh[4], bl[4];
        #pragma unroll
        for (int f = 0; f < 4; ++f) {
            const int ra = (fq * 128 + wm + f * 16 + fr) * 8;
            const int rb = (fq * 128 + wn + f * 16 + fr) * 8;
            ah[f] = *(const short8*)(Ah + ra);
            al[f] = *(const short8*)(Al + ra);
            bh[f] = *(const short8*)(Bh + rb);
            bl[f] = *(const short8*)(Bl + rb);
        }
        #pragma unroll
        for (int fm = 0; fm < 4; ++fm)
            #pragma unroll
            for (int fn = 0; fn < 4; ++fn) {
                acc[fm][fn] = __builtin_amdgcn_mfma_f32_16x16x32_bf16(ah[fm], bh[fn], acc[fm][fn], 0, 0, 0);
                acc[fm][fn] = __builtin_amdgcn_mfma_f32_16x16x32_bf16(ah[fm], bl[fn], acc[fm][fn], 0, 0, 0);
                acc[fm][fn] = __builtin_amdgcn_mfma_f32_16x16x32_bf16(al[fm], bh[fn], acc[fm][fn], 0, 0, 0);
            }
    }

    epilogue_H((float*)smem, acc, tid, wm, wn, fq, fr, Hb, s0, t0);
}

// ---------------------------------------------------------------------------
// Kernel 2 (v3, NEW): stencil + FUSED rescore. Stencil part is R10's
// validated 1-wave-per-query stencil_h verbatim. After the butterfly,
// k1/k2 are wave-uniform, so the same wave runs rescore6's logic inline:
// identical eul (lanes 0-8 / 16-24), identical gap test, and for the rare
// non-skipped queries the exact dot products for p1 then p2 sequentially
// (same lane*4 channel map, same fmaf order per candidate, same tie-break).
// Deletes the separate rescore launch + cand2 roundtrip. All branches are
// wave-uniform; no syncthreads.
// ---------------------------------------------------------------------------
__global__ __launch_bounds__(256) void stencil_rescore(
    const unsigned short* __restrict__ H0,
    const float* __restrict__ enc_bias,
    const float* __restrict__ content_t, // [4][4096][256]
    const float* __restrict__ style_t,   // [4096][256]
    const float* __restrict__ na_c,      // [4][4096] sum-of-squares
    const float* __restrict__ nb_s,      // [4096]    sum-of-squares
    int* __restrict__ idx, int bbase)
{
    const int bl = blockIdx.y;
    const unsigned short* H = H0 + (size_t)bl * SPSP;
    const int b = bbase + bl;

    const int q = blockIdx.x * 4 + (threadIdx.x >> 6);
    const int lane = threadIdx.x & 63;
    const int y = q / ND, x = q - y * ND;
    const int jg = (lane & 7) * 8;
    const int ig = lane >> 3;
    const unsigned short* Hq0 = H + (size_t)(y * 64 + x) * SP;
    const unsigned short* Hq1 = Hq0 + (size_t)64 * SP;
    const unsigned short* Hq2 = Hq0 + (size_t)128 * SP;

    float fb1[4], fb2[4];
    int   ib1[4], ib2[4];
    #pragma unroll
    for (int s = 0; s < 4; ++s) {
        fb1[s] = -3.0e38f; fb2[s] = -3.0e38f; ib1[s] = 0; ib2[s] = 0;
    }

    for (int it = 0; it < 8; ++it) {
        const int i = it * 8 + ig;
        if (i <= 61) {
            const int t0o = i * 64 + jg;
            half8 w0 = *(const half8*)(Hq0 + t0o);
            half8 w1 = *(const half8*)(Hq1 + t0o + 64);
            half8 w2 = *(const half8*)(Hq2 + t0o + 128);
            // enc bias: 8B-aligned float2 loads ((i*62+jg) even)
            const float* ep = enc_bias + i * ND + jg;
            float eb[8];
            {
                float2v a0 = *(const float2v*)(ep);
                float2v a1 = *(const float2v*)(ep + 2);
                float2v a2 = *(const float2v*)(ep + 4);
                eb[0] = a0[0]; eb[1] = a0[1];
                eb[2] = a1[0]; eb[3] = a1[1];
                eb[4] = a2[0]; eb[5] = a2[1];
                if (jg < 56) {
                    float2v a3 = *(const float2v*)(ep + 6);
                    eb[6] = a3[0]; eb[7] = a3[1];
                } else { eb[6] = 0.f; eb[7] = 0.f; }   // jj=62,63 masked anyway
            }
            const int pq = i * ND + jg;
            #pragma unroll
            for (int j = 0; j < 8; ++j) {
                int jj = jg + j;
                if (jj <= 61) {            // only jg=56, j>=6 masked
                    float fv = ((float)w0[j] + (float)w1[j])
                             + ((float)w2[j] + eb[j]);
                    int p = pq + j;
                    const int s = j >> 1;
                    bool gt1 = fv > fb1[s];
                    bool gt2 = fv > fb2[s];
                    fb2[s] = gt1 ? fb1[s] : (gt2 ? fv : fb2[s]);
                    ib2[s] = gt1 ? ib1[s] : (gt2 ? p  : ib2[s]);
                    fb1[s] = gt1 ? fv : fb1[s];
                    ib1[s] = gt1 ? p  : ib1[s];
                }
            }
        }
    }

    // --- per-lane merge: build 8 finalist keys, serial top-2 (validated) ---
    u64 k1 = 0, k2 = 0;
    #pragma unroll
    for (int s = 0; s < 4; ++s) {
        u64 ka = ((u64)orderf(fb1[s]) << 32) | (unsigned)(NP - 1 - ib1[s]);
        u64 kb = ((u64)orderf(fb2[s]) << 32) | (unsigned)(NP - 1 - ib2[s]);
        if (ka > k1) { k2 = k1; k1 = ka; } else if (ka > k2) k2 = ka;
        if (kb > k1) { k2 = k1; k1 = kb; } else if (kb > k2) k2 = kb;
    }

    // --- 64-lane butterfly (validated); k1/k2 wave-uniform after ---
    #pragma unroll
    for (int d = 1; d < 64; d <<= 1) {
        u64 o1 = __shfl_xor(k1, d, 64);
        u64 o2 = __shfl_xor(k2, d, 64);
        u64 hi = k1 > o1 ? k1 : o1;
        u64 lo = k1 > o1 ? o1 : k1;
        u64 m2 = k2 > o2 ? k2 : o2;
        k1 = hi;
        k2 = lo > m2 ? lo : m2;
    }

    // ===================== fused rescore (rescore6 logic) ==================
    const int qa = b * NP + q;
    const int p1 = NP - 1 - (int)(k1 & 0xffffffffu);
    const int p2 = NP - 1 - (int)(k2 & 0xffffffffu);
    const float f1 = unorderf((unsigned int)(k1 >> 32));
    const float f2 = unorderf((unsigned int)(k2 >> 32));

    if (k2 == 0ull) {
        if (lane == 0) idx[qa] = p1;
        return;
    }

    float eul = 0.f;
    {
        const int side = lane >> 4;            // lanes 0-8 -> p1, 16-24 -> p2
        const int d = lane & 15;
        if (side < 2 && d < 9) {
            int u = d / 3, v = d - u * 3;
            int pc = side ? p2 : p1;
            int pi = pc / ND, pj = pc - pi * ND;
            int sd = (y + u) * 64 + (x + v);
            int td = (pi + u) * 64 + (pj + v);
            float t = SPLIT_REL * sqrtf(na_c[b * SP + sd] * nb_s[td]);
            if (v == 0) {   // one full-ulp(H_fp16) per u (3 roundings total)
                unsigned short hh = H[(size_t)sd * SP + td];
                float hf = (float)(*(const _Float16*)&hh);
                t += __uint_as_float(__float_as_uint(hf) & 0x7f800000u) * HULP_H;
            }
            eul = t;
        }
    }
    #pragma unroll
    for (int d = 1; d < 64; d <<= 1) eul += __shfl_xor(eul, d, 64);

    if ((f1 - f2) > eul + EPS_G) {
        if (lane == 0) idx[qa] = p1;
        return;
    }

    // exact rescore: p1 then p2, each a 64-lane x 4-channel dot (same
    // fmaf order per candidate as rescore6)
    const float* ctb = content_t + (size_t)b * NCSP;
    float sc[2];
    #pragma unroll
    for (int c = 0; c < 2; ++c) {
        const int pc = c ? p2 : p1;
        const int pi = pc / ND, pj = pc - pi * ND;
        float s = 0.f;
        #pragma unroll
        for (int u = 0; u < 3; ++u) {
            #pragma unroll
            for (int v = 0; v < 3; ++v) {
                const float* cw = ctb + (size_t)((y + u) * 64 + x + v) * 256 + lane * 4;
                const float* sw = style_t + (size_t)((pi + u) * 64 + pj + v) * 256 + lane * 4;
                float4v c4 = *(const float4v*)cw;
                float4v s4 = *(const float4v*)sw;
                s = fmaf(c4[0], s4[0], s);
                s = fmaf(c4[1], s4[1], s);
                s = fmaf(c4[2], s4[2], s);
                s = fmaf(c4[3], s4[3], s);
            }
        }
        #pragma unroll
        for (int d = 32; d; d >>= 1) s += __shfl_xor(s, d, 64);
        sc[c] = s + enc_bias[pc];
    }
    if (lane == 0)
        idx[qa] = (sc[1] > sc[0] || (sc[1] == sc[0] && p2 < p1)) ? p2 : p1;
}

// ---------------------------------------------------------------------------
// Kernel 4 (v3, validated R9): gather-per-output-pixel with REGISTER
// accumulation; patch-row bases precomputed; bit-identical sums.
// ---------------------------------------------------------------------------
__global__ __launch_bounds__(256) void produce_out3(
    const float* __restrict__ style_t,
    const float* __restrict__ dec_bias,
    const float* __restrict__ intra_bias,
    const int* __restrict__ idx,
    float* __restrict__ out)
{
    __shared__ int prow[3][ND];   // pi*64+pj per (u, xx); add u*64+v at use

    const int bh = blockIdx.x;
    const int b = bh >> 6, h = bh & 63;
    const int ch0 = blockIdx.y * 128;
    const int tid = threadIdx.x;

    if (tid < 3 * ND) {
        int u = tid / ND, xx = tid - u * ND;
        int yy = h - u;
        int p = (yy >= 0 && yy < ND) ? idx[b * NP + yy * ND + xx] : 0;
        int pi = p / ND, pj = p - pi * ND;
        prow[u][xx] = pi * 64 + pj;
    }
    __syncthreads();

    const int w  = tid & 63;
    const int cg = tid >> 6;          // 0..3 -> 32 channels each
    const int cb = ch0 + cg * 32;

    float4v acc[8];
    #pragma unroll
    for (int i = 0; i < 8; ++i) acc[i] = (float4v)(0.f);

    #pragma unroll
    for (int u = 0; u < 3; ++u) {
        const int yy = h - u;
        if (yy >= 0 && yy < ND) {
            #pragma unroll
            for (int v = 0; v < 3; ++v) {
                const int xi = w - v;
                if (xi >= 0 && xi < ND) {
                    const int row = prow[u][xi] + u * 64 + v;
                    const float* sw = style_t + (size_t)row * 256 + cb;
                    #pragma unroll
                    for (int i = 0; i < 8; ++i) {
                        float4v s4 = *(const float4v*)(sw + i * 4);
                        acc[i] += s4;
                    }
                }
            }
        }
    }

    const int cu  = (h < 2 ? h : 2) - (h > 61 ? h - 61 : 0) + 1;
    const int cvw = (w < 2 ? w : 2) - (w > 61 ? w - 61 : 0) + 1;
    const float cnt = (float)(cu * cvw);
    #pragma unroll
    for (int i = 0; i < 8; ++i) {
        #pragma unroll
        for (int k = 0; k < 4; ++k) {
            const int c = cb + i * 4 + k;
            float val = (acc[i][k] + dec_bias[c]) / (cnt + intra_bias[c]);
            out[(((size_t)b * NC + c) * 64 + h) * 64 + w] = val;
        }
    }
}

// ---------------------------------------------------------------------------
extern "C" void kernel_launch(void* const* d_in, const int* in_sizes, int n_in,
                              void* d_out, int out_size, void* d_ws, size_t ws_size,
                              hipStream_t stream) {
    const float* content    = (const float*)d_in[0];
    const float* style      = (const float*)d_in[1];
    const float* enc_bias   = (const float*)d_in[2];
    const float* dec_bias   = (const float*)d_in[3];
    const float* intra_bias = (const float*)d_in[4];
    float* out = (float*)d_out;

    const size_t H_BYTES     = SPSP * 2;                   //  33,554,432
    const size_t CAND2_BYTES = (size_t)4 * NP * 2 * 8;     //     246,016 (unused, kept for layout)
    const size_t IDX_BYTES   = (size_t)4 * NP * 4;         //      61,504
    const size_t ST_BYTES    = NCSP * 4;                   //   4,194,304
    const size_t CT_BYTES    = (size_t)4 * NCSP * 4;       //  16,777,216
    const size_t P16_BYTES   = NCSP * 2;                   //   2,097,152
    const size_t NA_BYTES    = (size_t)4 * SP * 4;         //      65,536
    const size_t NB_BYTES    = (size_t)SP * 4;             //      16,384

    // Tier A: 4 H's resident + fp16 panels + transposes + norms
    const size_t A_OFF_CAND2 = 4 * H_BYTES;
    const size_t A_OFF_IDX   = A_OFF_CAND2 + CAND2_BYTES;
    const size_t A_OFF_ST    = A_OFF_IDX + IDX_BYTES;
    const size_t A_OFF_CT    = A_OFF_ST + ST_BYTES;
    const size_t A_OFF_PS    = A_OFF_CT + CT_BYTES;
    const size_t A_OFF_PC    = A_OFF_PS + P16_BYTES;
    const size_t A_OFF_NA    = A_OFF_PC + 4 * P16_BYTES;
    const size_t A_OFF_NB    = A_OFF_NA + NA_BYTES;
    const size_t NEED_A      = A_OFF_NB + NB_BYTES;

    // Tier B: single H + bf16x3 fp32-input GEMM per batch
    const size_t B_OFF_CAND2 = H_BYTES;
    const size_t B_OFF_IDX   = B_OFF_CAND2 + CAND2_BYTES;
    const size_t B_OFF_ST    = B_OFF_IDX + IDX_BYTES;
    const size_t B_OFF_CT    = B_OFF_ST + ST_BYTES;
    const size_t B_OFF_NA    = B_OFF_CT + CT_BYTES;
    const size_t B_OFF_NB    = B_OFF_NA + NA_BYTES;
    const size_t NEED_B      = B_OFF_NB + NB_BYTES;
    (void)NEED_B;

    if (ws_size >= NEED_A) {
        unsigned short* H4 = (unsigned short*)d_ws;
        int* idx        = (int*)((char*)d_ws + A_OFF_IDX);
        float* style_t  = (float*)((char*)d_ws + A_OFF_ST);
        float* content_t = (float*)((char*)d_ws + A_OFF_CT);
        unsigned short* PS = (unsigned short*)((char*)d_ws + A_OFF_PS);
        unsigned short* PC = (unsigned short*)((char*)d_ws + A_OFF_PC);
        float* na_c     = (float*)((char*)d_ws + A_OFF_NA);
        float* nb_s     = (float*)((char*)d_ws + A_OFF_NB);

        hipMemsetAsync((char*)d_ws + A_OFF_NA, 0, NA_BYTES + NB_BYTES, stream);
        prep_fused<<<dim3(16, 8, 5), 256, 0, stream>>>(
            content, style, content_t, style_t, PC, PS, na_c, nb_s);
        g_gemm_f16<<<dim3(33, 33, 4), 256, 0, stream>>>(PC, PS, H4);
        stencil_rescore<<<dim3(NP / 4, 4), 256, 0, stream>>>(
            H4, enc_bias, content_t, style_t, na_c, nb_s, idx, 0);
        produce_out3<<<dim3(4 * 64, 2), 256, 0, stream>>>(
            style_t, dec_bias, intra_bias, idx, out);
    } else {
        unsigned short* Hb = (unsigned short*)d_ws;
        int* idx        = (int*)((char*)d_ws + B_OFF_IDX);
        float* style_t  = (float*)((char*)d_ws + B_OFF_ST);
        float* content_t = (float*)((char*)d_ws + B_OFF_CT);
        float* na_c     = (float*)((char*)d_ws + B_OFF_NA);
        float* nb_s     = (float*)((char*)d_ws + B_OFF_NB);

        hipMemsetAsync((char*)d_ws + B_OFF_NA, 0, NA_BYTES + NB_BYTES, stream);
        transpose_b<<<dim3(128, 8, 1), 256, 0, stream>>>(style, style_t);
        transpose_b<<<dim3(128, 8, 4), 256, 0, stream>>>(content, content_t);
        col_sq<<<dim3(80, 4), 256, 0, stream>>>(content, style, na_c, nb_s);
        for (int b = 0; b < 4; ++b) {
            g_gemm<<<dim3(33, 33), 256, 0, stream>>>(
                content + (size_t)b * NCSP, style, Hb);
            stencil_rescore<<<dim3(NP / 4, 1), 256, 0, stream>>>(
                Hb, enc_bias, content_t, style_t, na_c, nb_s, idx, b);
        }
        produce_out3<<<dim3(4 * 64, 2), 256, 0, stream>>>(
            style_t, dec_bias, intra_bias, idx, out);
    }
}

// Round 13
// 236.931 us; speedup vs baseline: 1.0709x; 1.0021x over previous
//
#include <hip/hip_runtime.h>
#include <stdint.h>

// Problem constants (B=4, C=256, H=W=64, PATCH=3, STRIDE=1)
#define NP   3844   // 62*62 patches == per-batch feat pixels
#define ND   62
#define NC   256
#define HW   64
#define SP   4096   // 64*64 pixels per image
#define SPSP ((size_t)SP * SP)      // H elements per batch
#define NCSP ((size_t)NC * SP)      // panel elements per batch
#define EPS_G 0.15f        // margin: MFMA fp32 accum + stencil adds + subnormals
#define HULP_H 0.0009765625f // 2^-10: FULL ulp factor for fp16 H entries (RTZ hedge)
#define SPLIT_REL 0.0009765625f  // 2^-10: fp16 quantization of both GEMM operands

// Epilogue staging geometry: 65 rows x 132-float stride (34,320 B).
// R6: VGPR 84-92 caps occupancy at 16 waves/CU; LDS<40KB buys nothing.
// R7: barriered LDS-dbuf pipeline <= flat barrier-free loop. Keep R5 flat.
// R8/R9/R10: downstream kernels are L3-resident; traffic math overestimates.
// R11: 2-wave stencil split REGRESSED — 1 wave/query is right.
// R12: rescore fused into stencil wave (-7us). R13: vertical query grouping
// (block = 4 queries same x, y..y+3) halves H-row re-reads (12->6 rows/blk).
#define EP_ROWS 65
#define EP_LD   132

typedef __attribute__((ext_vector_type(8))) short short8;
typedef __attribute__((ext_vector_type(8))) unsigned short ushort8;
typedef __attribute__((ext_vector_type(8))) _Float16 half8;
typedef __attribute__((ext_vector_type(2))) _Float16 half2v;
typedef __attribute__((ext_vector_type(4))) float float4v;
typedef __attribute__((ext_vector_type(2))) float float2v;
typedef unsigned long long u64;

__device__ __forceinline__ unsigned int orderf(float v) {
    unsigned int u = __float_as_uint(v);
    return (u & 0x80000000u) ? ~u : (u | 0x80000000u);
}
__device__ __forceinline__ float unorderf(unsigned int k) {
    return __uint_as_float((k & 0x80000000u) ? (k ^ 0x80000000u) : ~k);
}

// Bijective XCD-aware block-id swizzle (m204 variant): contiguous chunk per
// XCD so per-XCD L2 caches one batch's panels. Bijective for any nwg.
__device__ __forceinline__ int xcd_swz(int orig, int nwg) {
    const int q = nwg >> 3, r = nwg & 7;
    const int xcd = orig & 7, i = orig >> 3;
    const int base = (xcd < r) ? xcd * (q + 1) : r * (q + 1) + (xcd - r) * q;
    return base + i;
}

// ---------------------------------------------------------------------------
// Kernel 0 (tier-B only): batched [256][4096] -> [4096][256] fp32 transpose
// ---------------------------------------------------------------------------
__global__ __launch_bounds__(256) void transpose_b(
    const float* __restrict__ src0, float* __restrict__ dst0)
{
    const float* src = src0 + (size_t)blockIdx.z * NCSP;
    float* dst = dst0 + (size_t)blockIdx.z * NCSP;
    __shared__ float t[32][33];
    const int s0 = blockIdx.x * 32;
    const int c0 = blockIdx.y * 32;
    const int col = threadIdx.x & 31, r8 = threadIdx.x >> 5;
    #pragma unroll
    for (int i = 0; i < 4; ++i) {
        int r = r8 + i * 8;
        t[r][col] = src[(size_t)(c0 + r) * SP + s0 + col];
    }
    __syncthreads();
    #pragma unroll
    for (int i = 0; i < 4; ++i) {
        int r = r8 + i * 8;
        dst[(size_t)(s0 + r) * 256 + c0 + col] = t[col][r];
    }
}

// ---------------------------------------------------------------------------
// Kernel 0b (tier-B only): column sum-of-squares, c split 4-way.
// ---------------------------------------------------------------------------
__global__ __launch_bounds__(256) void col_sq(
    const float* __restrict__ content, const float* __restrict__ style,
    float* __restrict__ na_c, float* __restrict__ nb_s)
{
    const int blk = blockIdx.x, tid = threadIdx.x, qn = blockIdx.y;
    const float* src;
    float* dst;
    int s;
    if (blk < 64) {
        int b = blk >> 4, ch = blk & 15;
        src = content + (size_t)b * NCSP;
        dst = na_c + b * SP;
        s = ch * 256 + tid;
    } else {
        src = style;
        dst = nb_s;
        s = (blk - 64) * 256 + tid;
    }
    float sum = 0.f;
    const int c0 = qn * 64;
    #pragma unroll 4
    for (int c = c0; c < c0 + 64; ++c) {
        float v = src[(size_t)c * SP + s];
        sum = fmaf(v, v, sum);
    }
    atomicAdd(&dst[s], sum);
}

// ---------------------------------------------------------------------------
// Kernel 0c (tier A, validated R10): FUSED prep — one read of the input:
//  (1) fp32 transpose [s][c], (2) fp16 RNE k-panels, (3) column sum-sq.
// grid (16,8,5): z 0..3 content, 4 style.
// ---------------------------------------------------------------------------
__global__ __launch_bounds__(256) void prep_fused(
    const float* __restrict__ content, const float* __restrict__ style,
    float* __restrict__ content_t, float* __restrict__ style_t,
    unsigned short* __restrict__ PC, unsigned short* __restrict__ PS,
    float* __restrict__ na_c, float* __restrict__ nb_s)
{
    __shared__ float t[32][257];
    const int z = blockIdx.z;
    const float* src;
    float* dt;
    unsigned short* pp;
    float* sqp;
    if (z < 4) {
        src = content + (size_t)z * NCSP;
        dt  = content_t + (size_t)z * NCSP;
        pp  = PC + (size_t)z * NCSP;
        sqp = na_c + z * SP;
    } else {
        src = style;
        dt  = style_t;
        pp  = PS;
        sqp = nb_s;
    }
    const int s0 = blockIdx.x * 256;
    const int c0 = blockIdx.y * 32;
    const int tid = threadIdx.x;

    // load 32 channel-rows x 256 columns (1KB coalesced per row)
    #pragma unroll
    for (int c = 0; c < 32; ++c)
        t[c][tid] = src[(size_t)(c0 + c) * SP + s0 + tid];
    __syncthreads();

    // (1) transpose: thread s=tid writes 32 consecutive c (8x float4)
    #pragma unroll
    for (int i = 0; i < 8; ++i) {
        float4v v;
        v[0] = t[4 * i + 0][tid];
        v[1] = t[4 * i + 1][tid];
        v[2] = t[4 * i + 2][tid];
        v[3] = t[4 * i + 3][tid];
        *(float4v*)(dt + (size_t)(s0 + tid) * 256 + c0 + 4 * i) = v;
    }

    // (2) fp16 panels: 4 kp-groups of 8 channels, 16B store each
    #pragma unroll
    for (int j = 0; j < 4; ++j) {
        ushort8 hv;
        #pragma unroll
        for (int kk = 0; kk < 8; ++kk) {
            _Float16 hf = (_Float16)t[j * 8 + kk][tid];   // RNE
            unsigned short hb;
            __builtin_memcpy(&hb, &hf, 2);
            hv[kk] = hb;
        }
        *(ushort8*)(pp + ((size_t)(c0 / 8 + j) * 4096 + s0 + tid) * 8) = hv;
    }

    // (3) column sum-of-squares over this block's 32 channels
    float sum = 0.f;
    #pragma unroll
    for (int c = 0; c < 32; ++c) {
        float x = t[c][tid];
        sum = fmaf(x, x, sum);
    }
    atomicAdd(&sqp[s0 + tid], sum);
}

// ---------------------------------------------------------------------------
// Shared GEMM epilogue (v2, validated R4/R5): TWO-PASS row-half staging
// through a padded float[65][132] LDS buffer. Pass p stages acc rows
// [63p, 63p+64], computes H rows 63p..63p+62:
//   H(s,t) = G(s,t)+G(s+1,t+1)+G(s+2,t+2), fp16 RNE.
// ---------------------------------------------------------------------------
__device__ __forceinline__ void epilogue_H(
    float* __restrict__ Lt, const float4v acc[4][4],
    int tid, int wm, int wn, int fq, int fr,
    unsigned short* __restrict__ Hb, int s0, int t0)
{
    #pragma unroll
    for (int p = 0; p < 2; ++p) {
        const int rb = p * 63;
        __syncthreads();   // orders prior reads / previous pass
        #pragma unroll
        for (int fm = 0; fm < 4; ++fm) {
            #pragma unroll
            for (int r = 0; r < 4; ++r) {
                const int row = wm + fm * 16 + fq * 4 + r;
                const int lr = row - rb;
                if (lr >= 0 && lr < EP_ROWS) {
                    #pragma unroll
                    for (int fn = 0; fn < 4; ++fn)
                        Lt[lr * EP_LD + wn + fn * 16 + fr] = acc[fm][fn][r];
                }
            }
        }
        __syncthreads();

        for (int task = tid; task < 63 * 16; task += 256) {
            const int rl = task >> 4;          // 0..62 local row
            const int rr = rb + rl;            // global tile row
            const int o  = (task & 15) * 8;
            const float* L0 = Lt + rl * EP_LD + o;
            const float* L1 = L0 + EP_LD;
            const float* L2 = L0 + 2 * EP_LD;
            float4v r0a = *(const float4v*)(L0);
            float4v r0b = *(const float4v*)(L0 + 4);
            float4v r1a = *(const float4v*)(L1);
            float4v r1b = *(const float4v*)(L1 + 4);
            float2v r1c = *(const float2v*)(L1 + 8);
            float4v r2a = *(const float4v*)(L2);
            float4v r2b = *(const float4v*)(L2 + 4);
            float2v r2c = *(const float2v*)(L2 + 8);
            float s_[8];
            s_[0] = r0a[0] + r1a[1] + r2a[2];
            s_[1] = r0a[1] + r1a[2] + r2a[3];
            s_[2] = r0a[2] + r1a[3] + r2b[0];
            s_[3] = r0a[3] + r1b[0] + r2b[1];
            s_[4] = r0b[0] + r1b[1] + r2b[2];
            s_[5] = r0b[1] + r1b[2] + r2b[3];
            s_[6] = r0b[2] + r1b[3] + r2c[0];
            s_[7] = r0b[3] + r1c[0] + r2c[1];
            unsigned short* hp = Hb + (size_t)(s0 + rr) * SP + t0 + o;
            const int kmax = (o == 120) ? 3 : 4;  // cols >=126: next tile's
            #pragma unroll
            for (int k = 0; k < 4; ++k) {
                if (k < kmax) {
                    half2v hv;
                    hv[0] = (_Float16)s_[2 * k];
                    hv[1] = (_Float16)s_[2 * k + 1];
                    *(half2v*)(hp + 2 * k) = hv;
                }
            }
        }
    }
}

// ---------------------------------------------------------------------------
// Kernel 1 (R5-exact, best measured): fp16 panel GEMM, FLAT barrier-free
// main loop (unroll 4) + XCD swizzle + fused two-pass H epilogue.
// ---------------------------------------------------------------------------
__global__ __launch_bounds__(256) void g_gemm_f16(
    const unsigned short* __restrict__ A0,
    const unsigned short* __restrict__ B,
    unsigned short* __restrict__ H0)
{
    __shared__ __attribute__((aligned(16))) float Lt[EP_ROWS * EP_LD];

    // --- bijective XCD swizzle over the flattened 33*33*4 grid ---
    const int orig = blockIdx.x + 33 * blockIdx.y + 1089 * blockIdx.z;
    const int wg = xcd_swz(orig, 4356);
    const int bz = wg / 1089;
    const int rem = wg - bz * 1089;
    const int by = rem / 33;
    const int bx = rem - by * 33;

    const unsigned short* A = A0 + (size_t)bz * NCSP;
    unsigned short* Hb = H0 + (size_t)bz * SPSP;

    const int tid  = threadIdx.x;
    const int s0   = (bx < 32) ? bx * 126 : 3968;
    const int t0   = (by < 32) ? by * 126 : 3968;
    const int wave = tid >> 6, lane = tid & 63;
    const int wm = (wave >> 1) * 64, wn = (wave & 1) * 64;
    const int fr = lane & 15;
    const int fq = lane >> 4;     // k-quad -> panel offset

    float4v acc[4][4];
    #pragma unroll
    for (int i = 0; i < 4; ++i)
        #pragma unroll
        for (int j = 0; j < 4; ++j) acc[i][j] = (float4v)(0.f);

    size_t ra0[4], rb0[4];
    #pragma unroll
    for (int f = 0; f < 4; ++f) {
        ra0[f] = ((size_t)fq * 4096 + s0 + wm + f * 16 + fr) * 8;
        rb0[f] = ((size_t)fq * 4096 + t0 + wn + f * 16 + fr) * 8;
    }

    #pragma unroll 4
    for (int ks = 0; ks < 8; ++ks) {
        const size_t pan = (size_t)ks * 4 * 4096 * 8;
        half8 a[4], b[4];
        #pragma unroll
        for (int f = 0; f < 4; ++f) {
            a[f] = *(const half8*)(A + pan + ra0[f]);
            b[f] = *(const half8*)(B + pan + rb0[f]);
        }
        #pragma unroll
        for (int fm = 0; fm < 4; ++fm)
            #pragma unroll
            for (int fn = 0; fn < 4; ++fn)
                acc[fm][fn] = __builtin_amdgcn_mfma_f32_16x16x32_f16(
                    a[fm], b[fn], acc[fm][fn], 0, 0, 0);
    }

    epilogue_H(Lt, acc, tid, wm, wn, fq, fr, Hb, s0, t0);
}

// ---------------------------------------------------------------------------
// Kernel 1-fallback: LDS-staged bf16x3 GEMM (fp32 in) + fused H epilogue
// ---------------------------------------------------------------------------
__global__ __launch_bounds__(256, 2) void g_gemm(
    const float* __restrict__ contentb,
    const float* __restrict__ style,
    unsigned short* __restrict__ Hb)
{
    __shared__ __attribute__((aligned(16))) char smem[65536];
    short* Ah = (short*)smem;           // 4*128*8 shorts each
    short* Al = Ah + 4096;
    short* Bh = Al + 4096;
    short* Bl = Bh + 4096;

    const int orig = blockIdx.x + 33 * blockIdx.y;
    const int wg = xcd_swz(orig, 1089);
    const int by = wg / 33;
    const int bx = wg - by * 33;

    const int tid  = threadIdx.x;
    const int s0   = (bx < 32) ? bx * 126 : 3968;
    const int t0   = (by < 32) ? by * 126 : 3968;
    const int wave = tid >> 6, lane = tid & 63;
    const int wm = (wave >> 1) * 64, wn = (wave & 1) * 64;
    const int fr = lane & 15;
    const int fq = lane >> 4;
    const int sm = tid & 127;
    const int sl = tid >> 7;

    float4v acc[4][4];
    #pragma unroll
    for (int i = 0; i < 4; ++i)
        #pragma unroll
        for (int j = 0; j < 4; ++j) acc[i][j] = (float4v)(0.f);

    for (int k0 = 0; k0 < 256; k0 += 32) {
        __syncthreads();
        #pragma unroll
        for (int h = 0; h < 2; ++h) {
            const float* src = h ? style : contentb;
            const int rb = h ? t0 : s0;
            short* dh = h ? Bh : Ah;
            short* dl = h ? Bl : Al;
            float v[16];
            #pragma unroll
            for (int j = 0; j < 16; ++j)
                v[j] = src[(size_t)(k0 + sl * 16 + j) * SP + rb + sm];
            short8 h0, h1, l0, l1;
            #pragma unroll
            for (int j = 0; j < 8; ++j) {
                unsigned ua = __float_as_uint(v[j]);
                unsigned ub = __float_as_uint(v[j + 8]);
                h0[j] = (short)(ua >> 16);
                h1[j] = (short)(ub >> 16);
                float ra  = v[j]     - __uint_as_float(ua & 0xffff0000u);
                float rb2 = v[j + 8] - __uint_as_float(ub & 0xffff0000u);
                l0[j] = (short)(__float_as_uint(ra) >> 16);
                l1[j] = (short)(__float_as_uint(rb2) >> 16);
            }
            *(short8*)(dh + ((sl * 2)     * 128 + sm) * 8) = h0;
            *(short8*)(dh + ((sl * 2 + 1) * 128 + sm) * 8) = h1;
            *(short8*)(dl + ((sl * 2)     * 128 + sm) * 8) = l0;
            *(short8*)(dl + ((sl * 2 + 1) * 128 + sm) * 8) = l1;
        }
        __syncthreads();

        short8 ah[4], al[4], bh[4], bl[4];
        #pragma unroll
        for (int f = 0; f < 4; ++f) {
            const int ra = (fq * 128 + wm + f * 16 + fr) * 8;
            const int rb = (fq * 128 + wn + f * 16 + fr) * 8;
            ah[f] = *(const short8*)(Ah + ra);
            al[f] = *(const short8*)(Al + ra);
            bh[f] = *(const short8*)(Bh + rb);
            bl[f] = *(const short8*)(Bl + rb);
        }
        #pragma unroll
        for (int fm = 0; fm < 4; ++fm)
            #pragma unroll
            for (int fn = 0; fn < 4; ++fn) {
                acc[fm][fn] = __builtin_amdgcn_mfma_f32_16x16x32_bf16(ah[fm], bh[fn], acc[fm][fn], 0, 0, 0);
                acc[fm][fn] = __builtin_amdgcn_mfma_f32_16x16x32_bf16(ah[fm], bl[fn], acc[fm][fn], 0, 0, 0);
                acc[fm][fn] = __builtin_amdgcn_mfma_f32_16x16x32_bf16(al[fm], bh[fn], acc[fm][fn], 0, 0, 0);
            }
    }

    epilogue_H((float*)smem, acc, tid, wm, wn, fq, fr, Hb, s0, t0);
}

// ---------------------------------------------------------------------------
// Kernel 2 (v4): stencil + fused rescore with VERTICAL query grouping.
// Block = 4 waves = queries (y..y+3, x): the 4 waves' H-row sets overlap
// (rows y*64+x + k*64, k=0..5 -> 6 distinct rows vs 12 for the horizontal
// mapping), halving the dominant L2/L3 read stream. All per-wave logic is
// R12's validated stencil_rescore verbatim; only the q decode changes.
// No barriers -> wave-uniform early exit for y >= 62 is safe.
// ---------------------------------------------------------------------------
__global__ __launch_bounds__(256) void stencil_rescore(
    const unsigned short* __restrict__ H0,
    const float* __restrict__ enc_bias,
    const float* __restrict__ content_t, // [4][4096][256]
    const float* __restrict__ style_t,   // [4096][256]
    const float* __restrict__ na_c,      // [4][4096] sum-of-squares
    const float* __restrict__ nb_s,      // [4096]    sum-of-squares
    int* __restrict__ idx, int bbase)
{
    const int bl = blockIdx.y;
    const unsigned short* H = H0 + (size_t)bl * SPSP;
    const int b = bbase + bl;

    // vertical grouping: grid.x = 16*62; x fast, y-group slow
    const int yg = blockIdx.x / ND;        // 0..15
    const int x  = blockIdx.x - yg * ND;   // 0..61
    const int y  = yg * 4 + (threadIdx.x >> 6);
    if (y >= ND) return;                   // wave-uniform (no barriers below)
    const int q = y * ND + x;

    const int lane = threadIdx.x & 63;
    const int jg = (lane & 7) * 8;
    const int ig = lane >> 3;
    const unsigned short* Hq0 = H + (size_t)(y * 64 + x) * SP;
    const unsigned short* Hq1 = Hq0 + (size_t)64 * SP;
    const unsigned short* Hq2 = Hq0 + (size_t)128 * SP;

    float fb1[4], fb2[4];
    int   ib1[4], ib2[4];
    #pragma unroll
    for (int s = 0; s < 4; ++s) {
        fb1[s] = -3.0e38f; fb2[s] = -3.0e38f; ib1[s] = 0; ib2[s] = 0;
    }

    for (int it = 0; it < 8; ++it) {
        const int i = it * 8 + ig;
        if (i <= 61) {
            const int t0o = i * 64 + jg;
            half8 w0 = *(const half8*)(Hq0 + t0o);
            half8 w1 = *(const half8*)(Hq1 + t0o + 64);
            half8 w2 = *(const half8*)(Hq2 + t0o + 128);
            // enc bias: 8B-aligned float2 loads ((i*62+jg) even)
            const float* ep = enc_bias + i * ND + jg;
            float eb[8];
            {
                float2v a0 = *(const float2v*)(ep);
                float2v a1 = *(const float2v*)(ep + 2);
                float2v a2 = *(const float2v*)(ep + 4);
                eb[0] = a0[0]; eb[1] = a0[1];
                eb[2] = a1[0]; eb[3] = a1[1];
                eb[4] = a2[0]; eb[5] = a2[1];
                if (jg < 56) {
                    float2v a3 = *(const float2v*)(ep + 6);
                    eb[6] = a3[0]; eb[7] = a3[1];
                } else { eb[6] = 0.f; eb[7] = 0.f; }   // jj=62,63 masked anyway
            }
            const int pq = i * ND + jg;
            #pragma unroll
            for (int j = 0; j < 8; ++j) {
                int jj = jg + j;
                if (jj <= 61) {            // only jg=56, j>=6 masked
                    float fv = ((float)w0[j] + (float)w1[j])
                             + ((float)w2[j] + eb[j]);
                    int p = pq + j;
                    const int s = j >> 1;
                    bool gt1 = fv > fb1[s];
                    bool gt2 = fv > fb2[s];
                    fb2[s] = gt1 ? fb1[s] : (gt2 ? fv : fb2[s]);
                    ib2[s] = gt1 ? ib1[s] : (gt2 ? p  : ib2[s]);
                    fb1[s] = gt1 ? fv : fb1[s];
                    ib1[s] = gt1 ? p  : ib1[s];
                }
            }
        }
    }

    // --- per-lane merge: build 8 finalist keys, serial top-2 (validated) ---
    u64 k1 = 0, k2 = 0;
    #pragma unroll
    for (int s = 0; s < 4; ++s) {
        u64 ka = ((u64)orderf(fb1[s]) << 32) | (unsigned)(NP - 1 - ib1[s]);
        u64 kb = ((u64)orderf(fb2[s]) << 32) | (unsigned)(NP - 1 - ib2[s]);
        if (ka > k1) { k2 = k1; k1 = ka; } else if (ka > k2) k2 = ka;
        if (kb > k1) { k2 = k1; k1 = kb; } else if (kb > k2) k2 = kb;
    }

    // --- 64-lane butterfly (validated); k1/k2 wave-uniform after ---
    #pragma unroll
    for (int d = 1; d < 64; d <<= 1) {
        u64 o1 = __shfl_xor(k1, d, 64);
        u64 o2 = __shfl_xor(k2, d, 64);
        u64 hi = k1 > o1 ? k1 : o1;
        u64 lo = k1 > o1 ? o1 : k1;
        u64 m2 = k2 > o2 ? k2 : o2;
        k1 = hi;
        k2 = lo > m2 ? lo : m2;
    }

    // ===================== fused rescore (rescore6 logic) ==================
    const int qa = b * NP + q;
    const int p1 = NP - 1 - (int)(k1 & 0xffffffffu);
    const int p2 = NP - 1 - (int)(k2 & 0xffffffffu);
    const float f1 = unorderf((unsigned int)(k1 >> 32));
    const float f2 = unorderf((unsigned int)(k2 >> 32));

    if (k2 == 0ull) {
        if (lane == 0) idx[qa] = p1;
        return;
    }

    float eul = 0.f;
    {
        const int side = lane >> 4;            // lanes 0-8 -> p1, 16-24 -> p2
        const int d = lane & 15;
        if (side < 2 && d < 9) {
            int u = d / 3, v = d - u * 3;
            int pc = side ? p2 : p1;
            int pi = pc / ND, pj = pc - pi * ND;
            int sd = (y + u) * 64 + (x + v);
            int td = (pi + u) * 64 + (pj + v);
            float t = SPLIT_REL * sqrtf(na_c[b * SP + sd] * nb_s[td]);
            if (v == 0) {   // one full-ulp(H_fp16) per u (3 roundings total)
                unsigned short hh = H[(size_t)sd * SP + td];
                float hf = (float)(*(const _Float16*)&hh);
                t += __uint_as_float(__float_as_uint(hf) & 0x7f800000u) * HULP_H;
            }
            eul = t;
        }
    }
    #pragma unroll
    for (int d = 1; d < 64; d <<= 1) eul += __shfl_xor(eul, d, 64);

    if ((f1 - f2) > eul + EPS_G) {
        if (lane == 0) idx[qa] = p1;
        return;
    }

    // exact rescore: p1 then p2, each a 64-lane x 4-channel dot (same
    // fmaf order per candidate as rescore6)
    const float* ctb = content_t + (size_t)b * NCSP;
    float sc[2];
    #pragma unroll
    for (int c = 0; c < 2; ++c) {
        const int pc = c ? p2 : p1;
        const int pi = pc / ND, pj = pc - pi * ND;
        float s = 0.f;
        #pragma unroll
        for (int u = 0; u < 3; ++u) {
            #pragma unroll
            for (int v = 0; v < 3; ++v) {
                const float* cw = ctb + (size_t)((y + u) * 64 + x + v) * 256 + lane * 4;
                const float* sw = style_t + (size_t)((pi + u) * 64 + pj + v) * 256 + lane * 4;
                float4v c4 = *(const float4v*)cw;
                float4v s4 = *(const float4v*)sw;
                s = fmaf(c4[0], s4[0], s);
                s = fmaf(c4[1], s4[1], s);
                s = fmaf(c4[2], s4[2], s);
                s = fmaf(c4[3], s4[3], s);
            }
        }
        #pragma unroll
        for (int d = 32; d; d >>= 1) s += __shfl_xor(s, d, 64);
        sc[c] = s + enc_bias[pc];
    }
    if (lane == 0)
        idx[qa] = (sc[1] > sc[0] || (sc[1] == sc[0] && p2 < p1)) ? p2 : p1;
}

// ---------------------------------------------------------------------------
// Kernel 4 (v3, validated R9): gather-per-output-pixel with REGISTER
// accumulation; patch-row bases precomputed; bit-identical sums.
// ---------------------------------------------------------------------------
__global__ __launch_bounds__(256) void produce_out3(
    const float* __restrict__ style_t,
    const float* __restrict__ dec_bias,
    const float* __restrict__ intra_bias,
    const int* __restrict__ idx,
    float* __restrict__ out)
{
    __shared__ int prow[3][ND];   // pi*64+pj per (u, xx); add u*64+v at use

    const int bh = blockIdx.x;
    const int b = bh >> 6, h = bh & 63;
    const int ch0 = blockIdx.y * 128;
    const int tid = threadIdx.x;

    if (tid < 3 * ND) {
        int u = tid / ND, xx = tid - u * ND;
        int yy = h - u;
        int p = (yy >= 0 && yy < ND) ? idx[b * NP + yy * ND + xx] : 0;
        int pi = p / ND, pj = p - pi * ND;
        prow[u][xx] = pi * 64 + pj;
    }
    __syncthreads();

    const int w  = tid & 63;
    const int cg = tid >> 6;          // 0..3 -> 32 channels each
    const int cb = ch0 + cg * 32;

    float4v acc[8];
    #pragma unroll
    for (int i = 0; i < 8; ++i) acc[i] = (float4v)(0.f);

    #pragma unroll
    for (int u = 0; u < 3; ++u) {
        const int yy = h - u;
        if (yy >= 0 && yy < ND) {
            #pragma unroll
            for (int v = 0; v < 3; ++v) {
                const int xi = w - v;
                if (xi >= 0 && xi < ND) {
                    const int row = prow[u][xi] + u * 64 + v;
                    const float* sw = style_t + (size_t)row * 256 + cb;
                    #pragma unroll
                    for (int i = 0; i < 8; ++i) {
                        float4v s4 = *(const float4v*)(sw + i * 4);
                        acc[i] += s4;
                    }
                }
            }
        }
    }

    const int cu  = (h < 2 ? h : 2) - (h > 61 ? h - 61 : 0) + 1;
    const int cvw = (w < 2 ? w : 2) - (w > 61 ? w - 61 : 0) + 1;
    const float cnt = (float)(cu * cvw);
    #pragma unroll
    for (int i = 0; i < 8; ++i) {
        #pragma unroll
        for (int k = 0; k < 4; ++k) {
            const int c = cb + i * 4 + k;
            float val = (acc[i][k] + dec_bias[c]) / (cnt + intra_bias[c]);
            out[(((size_t)b * NC + c) * 64 + h) * 64 + w] = val;
        }
    }
}

// ---------------------------------------------------------------------------
extern "C" void kernel_launch(void* const* d_in, const int* in_sizes, int n_in,
                              void* d_out, int out_size, void* d_ws, size_t ws_size,
                              hipStream_t stream) {
    const float* content    = (const float*)d_in[0];
    const float* style      = (const float*)d_in[1];
    const float* enc_bias   = (const float*)d_in[2];
    const float* dec_bias   = (const float*)d_in[3];
    const float* intra_bias = (const float*)d_in[4];
    float* out = (float*)d_out;

    const size_t H_BYTES     = SPSP * 2;                   //  33,554,432
    const size_t CAND2_BYTES = (size_t)4 * NP * 2 * 8;     //     246,016 (unused, kept for layout)
    const size_t IDX_BYTES   = (size_t)4 * NP * 4;         //      61,504
    const size_t ST_BYTES    = NCSP * 4;                   //   4,194,304
    const size_t CT_BYTES    = (size_t)4 * NCSP * 4;       //  16,777,216
    const size_t P16_BYTES   = NCSP * 2;                   //   2,097,152
    const size_t NA_BYTES    = (size_t)4 * SP * 4;         //      65,536
    const size_t NB_BYTES    = (size_t)SP * 4;             //      16,384

    // Tier A: 4 H's resident + fp16 panels + transposes + norms
    const size_t A_OFF_CAND2 = 4 * H_BYTES;
    const size_t A_OFF_IDX   = A_OFF_CAND2 + CAND2_BYTES;
    const size_t A_OFF_ST    = A_OFF_IDX + IDX_BYTES;
    const size_t A_OFF_CT    = A_OFF_ST + ST_BYTES;
    const size_t A_OFF_PS    = A_OFF_CT + CT_BYTES;
    const size_t A_OFF_PC    = A_OFF_PS + P16_BYTES;
    const size_t A_OFF_NA    = A_OFF_PC + 4 * P16_BYTES;
    const size_t A_OFF_NB    = A_OFF_NA + NA_BYTES;
    const size_t NEED_A      = A_OFF_NB + NB_BYTES;

    // Tier B: single H + bf16x3 fp32-input GEMM per batch
    const size_t B_OFF_CAND2 = H_BYTES;
    const size_t B_OFF_IDX   = B_OFF_CAND2 + CAND2_BYTES;
    const size_t B_OFF_ST    = B_OFF_IDX + IDX_BYTES;
    const size_t B_OFF_CT    = B_OFF_ST + ST_BYTES;
    const size_t B_OFF_NA    = B_OFF_CT + CT_BYTES;
    const size_t B_OFF_NB    = B_OFF_NA + NA_BYTES;
    const size_t NEED_B      = B_OFF_NB + NB_BYTES;
    (void)NEED_B;

    if (ws_size >= NEED_A) {
        unsigned short* H4 = (unsigned short*)d_ws;
        int* idx        = (int*)((char*)d_ws + A_OFF_IDX);
        float* style_t  = (float*)((char*)d_ws + A_OFF_ST);
        float* content_t = (float*)((char*)d_ws + A_OFF_CT);
        unsigned short* PS = (unsigned short*)((char*)d_ws + A_OFF_PS);
        unsigned short* PC = (unsigned short*)((char*)d_ws + A_OFF_PC);
        float* na_c     = (float*)((char*)d_ws + A_OFF_NA);
        float* nb_s     = (float*)((char*)d_ws + A_OFF_NB);

        hipMemsetAsync((char*)d_ws + A_OFF_NA, 0, NA_BYTES + NB_BYTES, stream);
        prep_fused<<<dim3(16, 8, 5), 256, 0, stream>>>(
            content, style, content_t, style_t, PC, PS, na_c, nb_s);
        g_gemm_f16<<<dim3(33, 33, 4), 256, 0, stream>>>(PC, PS, H4);
        stencil_rescore<<<dim3(16 * ND, 4), 256, 0, stream>>>(
            H4, enc_bias, content_t, style_t, na_c, nb_s, idx, 0);
        produce_out3<<<dim3(4 * 64, 2), 256, 0, stream>>>(
            style_t, dec_bias, intra_bias, idx, out);
    } else {
        unsigned short* Hb = (unsigned short*)d_ws;
        int* idx        = (int*)((char*)d_ws + B_OFF_IDX);
        float* style_t  = (float*)((char*)d_ws + B_OFF_ST);
        float* content_t = (float*)((char*)d_ws + B_OFF_CT);
        float* na_c     = (float*)((char*)d_ws + B_OFF_NA);
        float* nb_s     = (float*)((char*)d_ws + B_OFF_NB);

        hipMemsetAsync((char*)d_ws + B_OFF_NA, 0, NA_BYTES + NB_BYTES, stream);
        transpose_b<<<dim3(128, 8, 1), 256, 0, stream>>>(style, style_t);
        transpose_b<<<dim3(128, 8, 4), 256, 0, stream>>>(content, content_t);
        col_sq<<<dim3(80, 4), 256, 0, stream>>>(content, style, na_c, nb_s);
        for (int b = 0; b < 4; ++b) {
            g_gemm<<<dim3(33, 33), 256, 0, stream>>>(
                content + (size_t)b * NCSP, style, Hb);
            stencil_rescore<<<dim3(16 * ND, 1), 256, 0, stream>>>(
                Hb, enc_bias, content_t, style_t, na_c, nb_s, idx, b);
        }
        produce_out3<<<dim3(4 * 64, 2), 256, 0, stream>>>(
            style_t, dec_bias, intra_bias, idx, out);
    }
}